// Round 1
// 668.868 us; speedup vs baseline: 1.0235x; 1.0235x over previous
//
#include <hip/hip_runtime.h>

#define NND 10000
#define EE  60000
#define DD  3000
#define HH  512
#define LL  128
#define PP  256
#define NM  3000

// padded dims for the big MFMA GEMM (no tail guards in hot loop)
#define KP  3072            // 48 * 64
#define MP  10240           // 40 * 256
#define NW  1024            // [sW1|tW1] fused width, 4*256
#define KTILES (KP/64)      // 48
#define NITER  (KTILES/2)   // 24

typedef short bf16x8 __attribute__((ext_vector_type(8)));
typedef float f32x4 __attribute__((ext_vector_type(4)));

// All scratch lives in module BSS -> no dependency on harness ws_size.
__device__ __align__(256) char g_ws[(size_t)176 << 20];

__device__ __forceinline__ unsigned short f2b(float f){
    unsigned int x = __float_as_uint(f);
    unsigned int r = x + 0x7FFFu + ((x >> 16) & 1u);
    return (unsigned short)(r >> 16);
}
__device__ __forceinline__ float b2f(unsigned short u){
    return __uint_as_float(((unsigned int)u) << 16);
}
// uint holding 2 bf16 (low = col c, high = col c+1)
__device__ __forceinline__ float2 bpair(unsigned int u){
    float2 r;
    r.x = __uint_as_float(u << 16);
    r.y = __uint_as_float(u & 0xffff0000u);
    return r;
}
__device__ __forceinline__ unsigned int packb(float a, float b){
    return (unsigned int)f2b(a) | ((unsigned int)f2b(b) << 16);
}

__device__ __forceinline__ void gl_lds16(const void* g, void* l){
    __builtin_amdgcn_global_load_lds(
        (const __attribute__((address_space(1))) unsigned int*)g,
        (__attribute__((address_space(3))) unsigned int*)l, 16, 0, 0);
}

// ---------------- init / graph build ----------------

__global__ void init_k(int* degi, int* cursor, float* scal,
                       float* ptW, float* ntW, float* svecraw, int* ecnt){
    int i = blockIdx.x*256 + threadIdx.x;
    if (i < NND){ degi[i]=0; cursor[i]=0; }
    if (i < 16) scal[i]=0.f;
    if (i == 0) ecnt[0]=0;
    if (i < 128) svecraw[i]=0.f;
    if (i < HH){ ptW[i]=0.f; ntW[i]=0.f; }
}

__global__ void count_k(const int* __restrict__ ei, int* degi){
    int i = blockIdx.x*256 + threadIdx.x;
    if (i < EE) atomicAdd(&degi[ei[EE + i]], 1);
}

__global__ void flag_k(const int* __restrict__ perm, const int* __restrict__ shuf,
                       int* flag, int* negsrc){
    int i = blockIdx.x*256 + threadIdx.x;
    if (i < NND){
        int p = perm[i];
        if (i < NM){ flag[p] = 1; negsrc[p] = -1; }
        else       { flag[p] = 0; negsrc[p] = perm[NM + shuf[i - NM]]; }
    }
}

// dinv + CSR segment allocation (order-free; per-block scan, 1 atomic/block)
__global__ __launch_bounds__(256) void alloc_k(const int* __restrict__ degi,
                                               float* dinv, int* rowptr, int* ecnt){
    __shared__ int sb[256];
    __shared__ int bbase;
    int t = threadIdx.x;
    int i = blockIdx.x*256 + t;
    int v = (i < NND) ? degi[i] : 0;
    sb[t] = v;
    __syncthreads();
    for (int off = 1; off < 256; off <<= 1){
        int x = 0;
        if (t >= off) x = sb[t - off];
        __syncthreads();
        sb[t] += x;
        __syncthreads();
    }
    if (t == 255) bbase = atomicAdd(ecnt, sb[255]);
    __syncthreads();
    if (i < NND){
        rowptr[i] = bbase + sb[t] - v;
        dinv[i] = 1.f/sqrtf((float)(degi[i] + 1));
    }
}

__global__ void fill_k(const int* __restrict__ ei, const int* __restrict__ rowptr,
                       int* cursor, int* adj){
    int i = blockIdx.x*256 + threadIdx.x;
    if (i < EE){
        int d = ei[EE + i];
        int s = ei[i];
        int p = atomicAdd(&cursor[d], 1);
        adj[rowptr[d] + p] = s;
    }
}

// token @ W1 partial sums
__global__ __launch_bounds__(512) void tok_k(const float* __restrict__ posT,
        const float* __restrict__ negT,
        const float* __restrict__ sW1, const float* __restrict__ tW1,
        float* ptW, float* ntW){
    int b = blockIdx.x; int chunk = blockIdx.y; int j = threadIdx.x;
    const float* tok = b ? negT : posT;
    const float* Wm  = b ? tW1  : sW1;
    float acc = 0.f;
    int d0 = chunk * (DD/8), d1 = d0 + (DD/8);
    for (int d = d0; d < d1; ++d) acc += tok[d] * Wm[(long)d*HH + j];
    atomicAdd(&((b ? ntW : ptW)[j]), acc);
}

// ---------------- casts for MFMA path ----------------

__global__ __launch_bounds__(256) void cast_pad_x_k(const float* __restrict__ x,
                                                    unsigned short* __restrict__ xb){
    long idx = (long)blockIdx.x*256 + threadIdx.x;
    if (idx >= (long)MP*(KP/8)) return;
    int row = (int)(idx / (KP/8));
    int g   = (int)(idx % (KP/8));
    unsigned short o[8] = {0,0,0,0,0,0,0,0};
    if (row < NND && g < DD/8){
        const float* src = x + (long)row*DD + g*8;
        float4 a = *(const float4*)(src);
        float4 b = *(const float4*)(src + 4);
        o[0]=f2b(a.x); o[1]=f2b(a.y); o[2]=f2b(a.z); o[3]=f2b(a.w);
        o[4]=f2b(b.x); o[5]=f2b(b.y); o[6]=f2b(b.z); o[7]=f2b(b.w);
    }
    *(uint4*)(xb + (long)row*KP + g*8) = *(const uint4*)o;
}

// batched transpose-cast: out[c*OS + r] = bf16(in[r*C + c]), zero-fill r in [R,OS)
struct TBatch {
    const float* in[10];
    unsigned short* out[10];
    int R[10], C[10], OS[10];
    int t0[11];
};

__global__ void transbatch_k(TBatch tb){
    __shared__ unsigned short tile[32][33];
    int b = blockIdx.x;
    int d = 0;
    while (d < 9 && b >= tb.t0[d+1]) d++;
    const float* in = tb.in[d];
    unsigned short* out = tb.out[d];
    int R = tb.R[d], C = tb.C[d], OS = tb.OS[d];
    int lt = b - tb.t0[d];
    int Ctiles = (C + 31) >> 5;
    int rt = lt / Ctiles, ct = lt % Ctiles;
    int rb = rt*32, cb = ct*32;
    int tx = threadIdx.x, ty = threadIdx.y; // (32,8)
    for (int i = ty; i < 32; i += 8){
        int r = rb + i, c = cb + tx;
        tile[i][tx] = (r < R && c < C) ? f2b(in[(long)r*C + c]) : (unsigned short)0;
    }
    __syncthreads();
    for (int i = ty; i < 32; i += 8){
        int c = cb + i, r = rb + tx;
        if (c < C && r < OS) out[(long)c*OS + r] = (r < R) ? tile[tx][i] : (unsigned short)0;
    }
}

// ---------------- 256x256 8-phase MFMA GEMM (T1+T2+T3+T4+T5), bf16 out ----------------
// A: MP x KP bf16, Bg: NW x KP bf16 (row = output col). C guarded to M rows.
// LDS layout per matrix: [buf(2)][khalf(2)][row(256)][32 elems], 64-B rows,
// XOR-swizzled: physical chunk = logical chunk ^ (((row>>3)&1)<<1).
// Staging: global_load_lds writes linearly (wave base + lane*16); the global
// source chunk is pre-swizzled so LDS content matches the swizzled read addr.

#define DS_A(MT, KS, BUF) (*(const bf16x8*)&As[((BUF)<<14) + ((KS)<<13) + a_off + ((MT)<<9)])
#define DS_B(NT, KS, BUF) (*(const bf16x8*)&Bs[((BUF)<<14) + ((KS)<<13) + b_off + ((NT)<<9)])

#define PHASE(MQ, BUF, STAGE_STMT, GATE_STMT) {                                  \
    bf16x8 a0k0 = DS_A(2*(MQ),   0, BUF);                                        \
    bf16x8 a0k1 = DS_A(2*(MQ),   1, BUF);                                        \
    bf16x8 a1k0 = DS_A(2*(MQ)+1, 0, BUF);                                        \
    bf16x8 a1k1 = DS_A(2*(MQ)+1, 1, BUF);                                        \
    if ((MQ) == 0){                                                              \
        _Pragma("unroll")                                                        \
        for (int nt = 0; nt < 4; ++nt){                                          \
            bfr[nt][0] = DS_B(nt, 0, BUF);                                       \
            bfr[nt][1] = DS_B(nt, 1, BUF);                                       \
        }                                                                        \
    }                                                                            \
    STAGE_STMT;                                                                  \
    __builtin_amdgcn_s_barrier();                                                \
    asm volatile("s_waitcnt lgkmcnt(0)" ::: "memory");                           \
    __builtin_amdgcn_sched_barrier(0);                                           \
    __builtin_amdgcn_s_setprio(1);                                               \
    _Pragma("unroll")                                                            \
    for (int nt = 0; nt < 4; ++nt){                                              \
        acc[2*(MQ)][nt]   = __builtin_amdgcn_mfma_f32_16x16x32_bf16(a0k0, bfr[nt][0], acc[2*(MQ)][nt],   0,0,0); \
        acc[2*(MQ)][nt]   = __builtin_amdgcn_mfma_f32_16x16x32_bf16(a0k1, bfr[nt][1], acc[2*(MQ)][nt],   0,0,0); \
        acc[2*(MQ)+1][nt] = __builtin_amdgcn_mfma_f32_16x16x32_bf16(a1k0, bfr[nt][0], acc[2*(MQ)+1][nt], 0,0,0); \
        acc[2*(MQ)+1][nt] = __builtin_amdgcn_mfma_f32_16x16x32_bf16(a1k1, bfr[nt][1], acc[2*(MQ)+1][nt], 0,0,0); \
    }                                                                            \
    __builtin_amdgcn_s_setprio(0);                                               \
    GATE_STMT;                                                                   \
    __builtin_amdgcn_s_barrier();                                                \
}

#define GATE4 asm volatile("s_waitcnt vmcnt(4)" ::: "memory")
#define GATE0 asm volatile("s_waitcnt vmcnt(0)" ::: "memory")
#define NOOPS ((void)0)

__global__ __launch_bounds__(512, 2) void gemm256(
    const unsigned short* __restrict__ Ag,
    const unsigned short* __restrict__ Bg,
    unsigned short* __restrict__ C,
    int M, int Cstride)
{
    __shared__ __align__(1024) unsigned short As[2*2*256*32];
    __shared__ __align__(1024) unsigned short Bs[2*2*256*32];

    // bijective XCD-chunked swizzle (nwg = 160, 160 % 8 == 0)
    const int nwg = (MP/256)*(NW/256);
    const int bid = blockIdx.y*gridDim.x + blockIdx.x;
    const int swz = (bid & 7)*(nwg >> 3) + (bid >> 3);
    const int m0 = (swz >> 2) * 256;   // gridDim.x == 4
    const int n0 = (swz & 3) * 256;

    const int tid = threadIdx.x;
    const int w   = tid >> 6,  l = tid & 63;
    const int wr  = w >> 2,    wc = w & 3;      // 2(M) x 4(N) wave grid
    const int l16 = l & 15,    quad = l >> 4;

    // staging constants: lane l writes LDS row (w*16 + l>>2), physical chunk (l&3)
    const int srow   = (w << 4) + (l >> 2);              // row within 128-row half
    const int schunk = (l & 3) ^ (((l >> 5) & 1) << 1);  // pre-swizzled global chunk
    // read constants: logical chunk 'quad' -> physical chunk quad^(((row>>3)&1)<<1)
    const int rq8   = ((quad ^ (((l16 >> 3) & 1) << 1)) << 3);
    const int a_off = ((wr*128 + l16) << 5) + rq8;
    const int b_off = ((wc*64  + l16) << 5) + rq8;

    f32x4 acc[8][4];
    #pragma unroll
    for (int i = 0; i < 8; ++i)
        #pragma unroll
        for (int j = 0; j < 4; ++j)
            #pragma unroll
            for (int r = 0; r < 4; ++r) acc[i][j][r] = 0.f;

    bf16x8 bfr[4][2];

    auto STG = [&](const unsigned short* G, int rowbase, int kt, int half,
                   unsigned short* lds, int buf){
        const unsigned short* g0 = G + (long)(rowbase + half*128 + srow)*KP
                                     + (kt << 6) + (schunk << 3);
        unsigned short* d0 = lds + (buf << 14) + ((half*128 + (w << 4)) << 5);
        gl_lds16(g0,      d0);             // k-half 0
        gl_lds16(g0 + 32, d0 + (1 << 13)); // k-half 1
    };

    // prologue: tile0 A+B -> buf0, tile1 B -> buf1 (6 half-tiles), drain
    STG(Ag, m0, 0, 0, As, 0);
    STG(Ag, m0, 0, 1, As, 0);
    STG(Bg, n0, 0, 0, Bs, 0);
    STG(Bg, n0, 0, 1, Bs, 0);
    STG(Bg, n0, 1, 0, Bs, 1);
    STG(Bg, n0, 1, 1, Bs, 1);
    GATE0;
    __builtin_amdgcn_s_barrier();

    // main loop: iteration computes tiles (2it)->buf0 [ph0-3], (2it+1)->buf1 [ph4-7]
    // stages: ph0/1 A(2it+1)->buf1, ph2/3 B(2it+2)->buf0, ph4/5 A(2it+2)->buf0,
    //         ph6/7 B(2it+3)->buf1.  Counted gates vmcnt(4) at ph3/ph7 end.
    #pragma unroll 1
    for (int it = 0; it < NITER-1; ++it){
        const int t1 = 2*it + 1, s0 = 2*it + 2, s1 = 2*it + 3;
        PHASE(0, 0, STG(Ag, m0, t1, 0, As, 1), NOOPS)
        PHASE(1, 0, STG(Ag, m0, t1, 1, As, 1), NOOPS)
        PHASE(2, 0, STG(Bg, n0, s0, 0, Bs, 0), NOOPS)
        PHASE(3, 0, STG(Bg, n0, s0, 1, Bs, 0), GATE4)
        PHASE(0, 1, STG(Ag, m0, s0, 0, As, 0), NOOPS)
        PHASE(1, 1, STG(Ag, m0, s0, 1, As, 0), NOOPS)
        PHASE(2, 1, STG(Bg, n0, s1, 0, Bs, 1), NOOPS)
        PHASE(3, 1, STG(Bg, n0, s1, 1, Bs, 1), GATE4)
    }
    // peeled last iteration: tiles KTILES-2 (buf0) / KTILES-1 (buf1); only A of the
    // last tile still needs staging; truncated FIFO -> full drain at ph3.
    PHASE(0, 0, STG(Ag, m0, KTILES-1, 0, As, 1), NOOPS)
    PHASE(1, 0, STG(Ag, m0, KTILES-1, 1, As, 1), NOOPS)
    PHASE(2, 0, NOOPS, NOOPS)
    PHASE(3, 0, NOOPS, GATE0)
    PHASE(0, 1, NOOPS, NOOPS)
    PHASE(1, 1, NOOPS, NOOPS)
    PHASE(2, 1, NOOPS, NOOPS)
    PHASE(3, 1, NOOPS, NOOPS)

    // epilogue: C/D layout col=lane&15, row=quad*4+reg
    #pragma unroll
    for (int mt = 0; mt < 8; ++mt){
        const int rowb = m0 + wr*128 + mt*16 + quad*4;
        #pragma unroll
        for (int nt = 0; nt < 4; ++nt){
            const int col = n0 + wc*64 + nt*16 + l16;
            #pragma unroll
            for (int r = 0; r < 4; ++r){
                const int row = rowb + r;
                if (row < M) C[(long)row*Cstride + col] = f2b(acc[mt][nt][r]);
            }
        }
    }
}

// ---------------- 64x64 MFMA GEMM: C = A[ridx?] @ BT^T (+epi) ----------------
// A: MxK bf16, BT: NnxK bf16, K % 32 == 0. epi: 0 none, 1 +bias, 2 +bias+prelu.
// obf: output bf16 (else f32). ridx: optional A row gather.
__global__ __launch_bounds__(256) void gemm_bt_ex(
    const unsigned short* __restrict__ A,
    const unsigned short* __restrict__ BT,
    void* __restrict__ Cv,
    int M, int Nn, int K, int Cstride,
    const float* __restrict__ bias,
    const float* __restrict__ alpha,
    int epi, const int* __restrict__ ridx, int obf)
{
    __shared__ __align__(16) unsigned short As[64*40];
    __shared__ __align__(16) unsigned short Bs[64*40];
    const int m0 = blockIdx.y*64, n0 = blockIdx.x*64;
    const int t = threadIdx.x;
    const int lrow = t >> 2, lk = (t & 3) * 8;
    const int wave = t >> 6, lane = t & 63;
    const int quad = lane >> 4, l16 = lane & 15;
    f32x4 acc[4];
    #pragma unroll
    for (int i = 0; i < 4; i++)
        for (int j = 0; j < 4; j++) acc[i][j] = 0.f;

    const bool arv = (m0 + lrow) < M;
    const bool brv = (n0 + lrow) < Nn;
    long arow = 0;
    if (arv) arow = ridx ? (long)ridx[m0 + lrow] : (long)(m0 + lrow);
    const long arowbase = arow * K;
    const long browbase = (long)(n0 + lrow) * K;

    for (int k0 = 0; k0 < K; k0 += 32){
        int gk = k0 + lk;
        uint4 av = {0u,0u,0u,0u};
        uint4 bv = {0u,0u,0u,0u};
        if (arv) av = *(const uint4*)(A + arowbase + gk);
        if (brv) bv = *(const uint4*)(BT + browbase + gk);
        *(uint4*)(&As[lrow*40 + lk]) = av;
        *(uint4*)(&Bs[lrow*40 + lk]) = bv;
        __syncthreads();
        bf16x8 af = *(const bf16x8*)(&As[(wave*16 + l16)*40 + quad*8]);
        #pragma unroll
        for (int nt = 0; nt < 4; nt++){
            bf16x8 bfr = *(const bf16x8*)(&Bs[(nt*16 + l16)*40 + quad*8]);
            acc[nt] = __builtin_amdgcn_mfma_f32_16x16x32_bf16(af, bfr, acc[nt], 0, 0, 0);
        }
        __syncthreads();
    }

    const int rowb = m0 + wave*16 + quad*4;
    float aval = (epi == 2) ? alpha[0] : 0.f;
    #pragma unroll
    for (int nt = 0; nt < 4; nt++){
        int col = n0 + nt*16 + l16;
        if (col >= Nn) continue;
        float bvv = epi ? bias[col] : 0.f;
        #pragma unroll
        for (int r = 0; r < 4; r++){
            int row = rowb + r;
            if (row < M){
                float v = acc[nt][r] + bvv;
                if (epi == 2 && v < 0.f) v *= aval;
                if (obf) ((unsigned short*)Cv)[(long)row*Cstride + col] = f2b(v);
                else     ((float*)Cv)[(long)row*Cstride + col] = v;
            }
        }
    }
}

// ---------------- fused GCN layer-1 aggregation (pos + neg), bf16 I/O ----------------

__global__ __launch_bounds__(256) void agg1_k(const unsigned short* __restrict__ XW,
    const float* __restrict__ ptW, const float* __restrict__ ntW,
    const int* __restrict__ flag, const int* __restrict__ negsrc,
    const float* __restrict__ dinv, const int* __restrict__ rowptr,
    const int* __restrict__ degi, const int* __restrict__ adj,
    const float* __restrict__ sb1, const float* __restrict__ sav,
    const float* __restrict__ tb1, const float* __restrict__ tav,
    unsigned short* __restrict__ H1p, unsigned short* __restrict__ H1n)
{
    int i = blockIdx.x; int t = threadIdx.x;
    int c = 2*t;                       // cols c, c+1 in [0,512)
    float di = dinv[i];
    int rs = rowptr[i], re = rs + degi[i];
    float p0 = ptW[c], p1 = ptW[c+1];
    float n0v = ntW[c], n1v = ntW[c+1];
    int fi = flag[i];
    int nsi = negsrc[i]; if (nsi < 0) nsi = 0;
    float ffi = fi ? 1.f : 0.f;
    float2 xp = bpair(*(const unsigned int*)(XW + (long)i*1024 + c));
    float2 xn = bpair(*(const unsigned int*)(XW + (long)nsi*1024 + 512 + c));
    float pa0 = (xp.x + ffi*p0) * di;
    float pa1 = (xp.y + ffi*p1) * di;
    float na0 = (fi ? n0v : xn.x) * di;
    float na1 = (fi ? n1v : xn.y) * di;
    for (int e = rs; e < re; ++e){
        int s = adj[e]; float ds = dinv[s];
        int fs = flag[s];
        int ns = negsrc[s]; if (ns < 0) ns = 0;
        float ffs = fs ? 1.f : 0.f;
        float2 sp = bpair(*(const unsigned int*)(XW + (long)s*1024 + c));
        float2 sn = bpair(*(const unsigned int*)(XW + (long)ns*1024 + 512 + c));
        pa0 += (sp.x + ffs*p0) * ds;
        pa1 += (sp.y + ffs*p1) * ds;
        na0 += (fs ? n0v : sn.x) * ds;
        na1 += (fs ? n1v : sn.y) * ds;
    }
    float sa_ = sav[0], ta_ = tav[0];
    float v0 = di*pa0 + sb1[c];   if (v0 < 0.f) v0 *= sa_;
    float v1 = di*pa1 + sb1[c+1]; if (v1 < 0.f) v1 *= sa_;
    float w0 = di*na0 + tb1[c];   if (w0 < 0.f) w0 *= ta_;
    float w1 = di*na1 + tb1[c+1]; if (w1 < 0.f) w1 *= ta_;
    *(unsigned int*)(H1p + (long)i*512 + c) = packb(v0, v1);
    *(unsigned int*)(H1n + (long)i*512 + c) = packb(w0, w1);
}

__global__ __launch_bounds__(128) void agg128_k(const unsigned short* __restrict__ In,
    const float* __restrict__ dinv, const int* __restrict__ rowptr,
    const int* __restrict__ degi, const int* __restrict__ adj,
    const float* __restrict__ b2, const float* __restrict__ a2,
    unsigned short* __restrict__ Out)
{
    int i = blockIdx.x, t = threadIdx.x;
    float di = dinv[i];
    int rs = rowptr[i], re = rs + degi[i];
    float acc = b2f(In[(long)i*128 + t]) * di;
    for (int e = rs; e < re; ++e){
        int s = adj[e];
        acc += b2f(In[(long)s*128 + t]) * dinv[s];
    }
    float v = di*acc + b2[t];
    float a = a2[0]; if (v < 0.f) v *= a;
    Out[(long)i*128 + t] = f2b(v);
}

__global__ __launch_bounds__(128) void aggrec_k(const unsigned short* __restrict__ recPre,
    const float* __restrict__ dinv, const int* __restrict__ rowptr,
    const int* __restrict__ degi, const int* __restrict__ adj,
    const int* __restrict__ flag, const int* __restrict__ perm,
    unsigned short* __restrict__ recAgg)
{
    int b = blockIdx.x, t = threadIdx.x;
    int i = perm[b];
    float di = dinv[i];
    int rs = rowptr[i], re = rs + degi[i];
    float acc = 0.f; // self loop: i is a mask node -> rec row zeroed
    for (int e = rs; e < re; ++e){
        int s = adj[e];
        if (!flag[s]) acc += b2f(recPre[(long)s*128 + t]) * dinv[s];
    }
    recAgg[(long)b*128 + t] = f2b(di * acc);
}

// ---------------- DGI head ----------------

__global__ __launch_bounds__(128) void meanp_k(const float* __restrict__ posZ,
                                               float* svecraw){
    int j = threadIdx.x;
    int r0 = blockIdx.x*64, r1 = r0 + 64; if (r1 > NM) r1 = NM;
    float s = 0.f;
    for (int r = r0; r < r1; ++r) s += posZ[(long)r*128 + j];
    atomicAdd(&svecraw[j], s);
}

__global__ void ws_k(const float* __restrict__ dgiW, const float* __restrict__ svecraw,
                     float* wsv){
    __shared__ float s[128];
    int i = threadIdx.x; // 128
    s[i] = 1.f/(1.f + expf(-svecraw[i]/(float)NM));
    __syncthreads();
    float a = 0.f;
    for (int j = 0; j < 128; ++j) a += dgiW[i*128 + j] * s[j];
    wsv[i] = a;
}

__global__ __launch_bounds__(256) void dgi_k(const float* __restrict__ posZ,
    const float* __restrict__ negZ, const float* __restrict__ wsv, float* scal){
    int row = blockIdx.x*4 + (threadIdx.x >> 6);
    int lane = threadIdx.x & 63;
    if (row >= 2*NM) return;
    const float* Z = (row < NM) ? posZ : negZ;
    int r = (row < NM) ? row : row - NM;
    float v = Z[(long)r*128 + lane] * wsv[lane]
            + Z[(long)r*128 + 64 + lane] * wsv[64 + lane];
    for (int off = 32; off; off >>= 1) v += __shfl_down(v, off, 64);
    if (lane == 0){
        float d = 1.f/(1.f + expf(-v));
        float lg = (row < NM) ? logf(d + 1e-15f) : logf(1.f - d + 1e-15f);
        atomicAdd(&scal[(row < NM) ? 0 : 1], lg);
    }
}

// ---------------- cosine feature loss ----------------

__global__ __launch_bounds__(256) void cos_k(const float* __restrict__ x,
    const unsigned short* __restrict__ recMask, const int* __restrict__ perm,
    float* scal){
    int b = blockIdx.x, t = threadIdx.x;
    long xi = (long)perm[b]*DD;
    long ri = (long)b*DD;
    float dot = 0.f, nx = 0.f, nr = 0.f;
    for (int d = t; d < DD; d += 256){
        float xv = x[xi + d], rv = b2f(recMask[ri + d]);
        dot += xv*rv; nx += xv*xv; nr += rv*rv;
    }
    for (int off = 32; off; off >>= 1){
        dot += __shfl_down(dot, off, 64);
        nx  += __shfl_down(nx,  off, 64);
        nr  += __shfl_down(nr,  off, 64);
    }
    __shared__ float sd[4], sx[4], sr[4];
    int w = t >> 6, lane = t & 63;
    if (lane == 0){ sd[w] = dot; sx[w] = nx; sr[w] = nr; }
    __syncthreads();
    if (t == 0){
        float Dv = sd[0]+sd[1]+sd[2]+sd[3];
        float Xv = sx[0]+sx[1]+sx[2]+sx[3];
        float Rv = sr[0]+sr[1]+sr[2]+sr[3];
        float c = Dv/(fmaxf(sqrtf(Xv),1e-12f)*fmaxf(sqrtf(Rv),1e-12f));
        float e = 1.f - c;
        atomicAdd(&scal[2], e*e);
    }
}

__global__ void fin_k(const float* __restrict__ scal, float* out){
    float feat = scal[2]/(float)NM;
    float dgi  = -(scal[0]/(float)NM) - (scal[1]/(float)NM);
    out[0] = feat;
    out[1] = dgi;
}

// ---------------- launch ----------------

extern "C" void kernel_launch(void* const* d_in, const int* in_sizes, int n_in,
                              void* d_out, int out_size, void* d_ws, size_t ws_size,
                              hipStream_t stream) {
    (void)in_sizes; (void)n_in; (void)out_size; (void)d_ws; (void)ws_size;
    const float* x  = (const float*)d_in[0];
    const int* ei   = (const int*)d_in[1];
    const int* perm = (const int*)d_in[2];
    const int* shuf = (const int*)d_in[3];
    const float* sW1 = (const float*)d_in[4];
    const float* sb1 = (const float*)d_in[5];
    const float* sa  = (const float*)d_in[6];
    const float* sW2 = (const float*)d_in[7];
    const float* sb2 = (const float*)d_in[8];
    const float* tW1 = (const float*)d_in[9];
    const float* tb1 = (const float*)d_in[10];
    const float* ta  = (const float*)d_in[11];
    const float* tW2 = (const float*)d_in[12];
    const float* tb2 = (const float*)d_in[13];
    const float* pW1 = (const float*)d_in[14];
    const float* pb1 = (const float*)d_in[15];
    const float* pa  = (const float*)d_in[16];
    const float* pW2 = (const float*)d_in[17];
    const float* pb2 = (const float*)d_in[18];
    const float* tpW1 = (const float*)d_in[19];
    const float* tpb1 = (const float*)d_in[20];
    const float* tpa  = (const float*)d_in[21];
    const float* tpW2 = (const float*)d_in[22];
    const float* tpb2 = (const float*)d_in[23];
    const float* dgiW = (const float*)d_in[24];
    const float* posT = (const float*)d_in[25];
    const float* negT = (const float*)d_in[26];
    const float* e2dW = (const float*)d_in[27];
    const float* dW   = (const float*)d_in[28];
    const float* db   = (const float*)d_in[29];
    float* out = (float*)d_out;

    void* wsp = nullptr;
    hipGetSymbolAddress(&wsp, HIP_SYMBOL(g_ws));
    char* base = (char*)wsp;
    size_t off = 0;
    auto alloc = [&](size_t b){ size_t o = off; off = (off + b + 255) & ~(size_t)255; return o; };

    float* dinv    = (float*)(base + alloc(NND*4));
    int* degi      = (int*)  (base + alloc(NND*4));
    int* rowptr    = (int*)  (base + alloc(NND*4));
    int* cursor    = (int*)  (base + alloc(NND*4));
    int* adj       = (int*)  (base + alloc(EE*4));
    int* flag      = (int*)  (base + alloc(NND*4));
    int* negsrc    = (int*)  (base + alloc(NND*4));
    int* ecnt      = (int*)  (base + alloc(16*4));
    float* ptW     = (float*)(base + alloc(HH*4));
    float* ntW     = (float*)(base + alloc(HH*4));
    float* svecraw = (float*)(base + alloc(128*4));
    float* wsv     = (float*)(base + alloc(128*4));
    float* scal    = (float*)(base + alloc(16*4));

    unsigned short* xb    = (unsigned short*)(base + alloc((size_t)MP*KP*2));
    unsigned short* W1T   = (unsigned short*)(base + alloc((size_t)NW*KP*2));
    unsigned short* sW2T  = (unsigned short*)(base + alloc((size_t)LL*HH*2));
    unsigned short* tW2T  = (unsigned short*)(base + alloc((size_t)LL*HH*2));
    unsigned short* pW1T  = (unsigned short*)(base + alloc((size_t)PP*LL*2));
    unsigned short* pW2T  = (unsigned short*)(base + alloc((size_t)LL*PP*2));
    unsigned short* tpW1T = (unsigned short*)(base + alloc((size_t)PP*LL*2));
    unsigned short* tpW2T = (unsigned short*)(base + alloc((size_t)LL*PP*2));
    unsigned short* e2dWT = (unsigned short*)(base + alloc((size_t)LL*LL*2));
    unsigned short* dWT   = (unsigned short*)(base + alloc((size_t)DD*LL*2));

    unsigned short* XW      = (unsigned short*)(base + alloc((size_t)NND*1024*2));
    unsigned short* H1p     = (unsigned short*)(base + alloc((size_t)NND*512*2));
    unsigned short* H1n     = (unsigned short*)(base + alloc((size_t)NND*512*2));
    unsigned short* M2p     = (unsigned short*)(base + alloc((size_t)NND*128*2));
    unsigned short* M2n     = (unsigned short*)(base + alloc((size_t)NND*128*2));
    unsigned short* repP    = (unsigned short*)(base + alloc((size_t)NND*128*2));
    unsigned short* repN    = (unsigned short*)(base + alloc((size_t)NND*128*2));
    unsigned short* posH    = (unsigned short*)(base + alloc((size_t)NM*256*2));
    unsigned short* negH    = (unsigned short*)(base + alloc((size_t)NM*256*2));
    float* posZ             = (float*)(base + alloc((size_t)NM*128*4));
    float* negZ             = (float*)(base + alloc((size_t)NM*128*4));
    unsigned short* recPre  = (unsigned short*)(base + alloc((size_t)NND*128*2));
    unsigned short* recAgg  = (unsigned short*)(base + alloc((size_t)NM*128*2));
    unsigned short* recMask = (unsigned short*)(base + alloc((size_t)NM*DD*2));

    // ---- graph build (scan-free) ----
    init_k<<<(NND+255)/256, 256, 0, stream>>>(degi, cursor, scal, ptW, ntW, svecraw, ecnt);
    flag_k<<<(NND+255)/256, 256, 0, stream>>>(perm, shuf, flag, negsrc);
    count_k<<<(EE+255)/256, 256, 0, stream>>>(ei, degi);
    alloc_k<<<(NND+255)/256, 256, 0, stream>>>(degi, dinv, rowptr, ecnt);
    fill_k<<<(EE+255)/256, 256, 0, stream>>>(ei, rowptr, cursor, adj);
    tok_k<<<dim3(2,8), 512, 0, stream>>>(posT, negT, sW1, tW1, ptW, ntW);

    // ---- bf16 staging ----
    cast_pad_x_k<<<(int)(((long)MP*(KP/8) + 255)/256), 256, 0, stream>>>(x, xb);
    {
        TBatch tb;
        const float* ins[10] = {sW1, tW1, sW2, tW2, pW1, pW2, tpW1, tpW2, e2dW, dW};
        unsigned short* outs[10] = {W1T, W1T + (size_t)HH*KP, sW2T, tW2T, pW1T, pW2T,
                                    tpW1T, tpW2T, e2dWT, dWT};
        int Rs[10]  = {DD, DD, HH, HH, LL, PP, LL, PP, LL, LL};
        int Cs[10]  = {HH, HH, LL, LL, PP, LL, PP, LL, LL, DD};
        int OSs[10] = {KP, KP, HH, HH, LL, PP, LL, PP, LL, LL};
        int cum = 0;
        for (int d = 0; d < 10; d++){
            tb.in[d] = ins[d]; tb.out[d] = outs[d];
            tb.R[d] = Rs[d]; tb.C[d] = Cs[d]; tb.OS[d] = OSs[d];
            tb.t0[d] = cum;
            cum += (OSs[d]/32) * ((Cs[d] + 31)/32);
        }
        tb.t0[10] = cum;
        transbatch_k<<<cum, dim3(32,8), 0, stream>>>(tb);
    }

    // ---- encoder layer 1 (MFMA 256x256 8-phase, bf16 out) + fused aggregation ----
    gemm256<<<dim3(NW/256, MP/256), 512, 0, stream>>>(xb, W1T, XW, NND, 1024);
    agg1_k<<<NND, 256, 0, stream>>>(XW, ptW, ntW, flag, negsrc, dinv, rowptr, degi, adj,
                                    sb1, sa, tb1, ta, H1p, H1n);

    // ---- encoder layer 2 (MFMA) ----
    gemm_bt_ex<<<dim3(2,157), 256, 0, stream>>>(H1p, sW2T, M2p, NND, LL, HH, LL,
                                                nullptr, nullptr, 0, nullptr, 1);
    gemm_bt_ex<<<dim3(2,157), 256, 0, stream>>>(H1n, tW2T, M2n, NND, LL, HH, LL,
                                                nullptr, nullptr, 0, nullptr, 1);
    agg128_k<<<NND, 128, 0, stream>>>(M2p, dinv, rowptr, degi, adj, sb2, sa, repP);
    agg128_k<<<NND, 128, 0, stream>>>(M2n, dinv, rowptr, degi, adj, tb2, ta, repN);

    // ---- projections on mask rows (MFMA, gathered A via perm) ----
    gemm_bt_ex<<<dim3(4,47), 256, 0, stream>>>(repP, pW1T, posH, NM, PP, LL, PP,
                                               pb1, pa, 2, perm, 1);
    gemm_bt_ex<<<dim3(2,47), 256, 0, stream>>>(posH, pW2T, posZ, NM, LL, PP, LL,
                                               pb2, nullptr, 1, nullptr, 0);
    gemm_bt_ex<<<dim3(4,47), 256, 0, stream>>>(repN, tpW1T, negH, NM, PP, LL, PP,
                                               tpb1, tpa, 2, perm, 1);
    gemm_bt_ex<<<dim3(2,47), 256, 0, stream>>>(negH, tpW2T, negZ, NM, LL, PP, LL,
                                               tpb2, nullptr, 1, nullptr, 0);

    // ---- DGI loss ----
    meanp_k<<<47, 128, 0, stream>>>(posZ, svecraw);
    ws_k<<<1, 128, 0, stream>>>(dgiW, svecraw, wsv);
    dgi_k<<<(2*NM)/4, 256, 0, stream>>>(posZ, negZ, wsv, scal);

    // ---- decoder + feature loss (MFMA) ----
    gemm_bt_ex<<<dim3(2,157), 256, 0, stream>>>(repP, e2dWT, recPre, NND, LL, LL, LL,
                                                nullptr, nullptr, 0, nullptr, 1);
    aggrec_k<<<NM, 128, 0, stream>>>(recPre, dinv, rowptr, degi, adj, flag, perm, recAgg);
    gemm_bt_ex<<<dim3(47,47), 256, 0, stream>>>(recAgg, dWT, recMask, NM, DD, LL, DD,
                                                db, nullptr, 1, nullptr, 1);
    cos_k<<<NM, 256, 0, stream>>>(x, recMask, perm, scal);

    fin_k<<<1, 1, 0, stream>>>(scal, out);
}

// Round 2
// 659.400 us; speedup vs baseline: 1.0381x; 1.0144x over previous
//
#include <hip/hip_runtime.h>

#define NND 10000
#define EE  60000
#define DD  3000
#define HH  512
#define LL  128
#define PP  256
#define NM  3000

// padded dims for the big MFMA GEMM (no tail guards in hot loop)
#define KP  3072            // 48 * 64
#define MP  10240           // 32 * 320
#define NW  1024            // [sW1|tW1] fused width, 8*128
#define KTILES (KP/64)      // 48

// gemm320 tile geometry
#define BMT 320
#define BNT 128
#define AH_STR 10240        // elems per A k-half (320 rows x 32)
#define AB_STR 20480        // elems per A buf (2 k-halves)
#define BH_STR 4096         // elems per B k-half (128 rows x 32)
#define BB_STR 8192         // elems per B buf

typedef short bf16x8 __attribute__((ext_vector_type(8)));
typedef float f32x4 __attribute__((ext_vector_type(4)));

// All scratch lives in module BSS -> no dependency on harness ws_size.
__device__ __align__(256) char g_ws[(size_t)176 << 20];

__device__ __forceinline__ unsigned short f2b(float f){
    unsigned int x = __float_as_uint(f);
    unsigned int r = x + 0x7FFFu + ((x >> 16) & 1u);
    return (unsigned short)(r >> 16);
}
__device__ __forceinline__ float b2f(unsigned short u){
    return __uint_as_float(((unsigned int)u) << 16);
}
// uint holding 2 bf16 (low = col c, high = col c+1)
__device__ __forceinline__ float2 bpair(unsigned int u){
    float2 r;
    r.x = __uint_as_float(u << 16);
    r.y = __uint_as_float(u & 0xffff0000u);
    return r;
}
__device__ __forceinline__ unsigned int packb(float a, float b){
    return (unsigned int)f2b(a) | ((unsigned int)f2b(b) << 16);
}

__device__ __forceinline__ void gl_lds16(const void* g, void* l){
    __builtin_amdgcn_global_load_lds(
        (const __attribute__((address_space(1))) unsigned int*)g,
        (__attribute__((address_space(3))) unsigned int*)l, 16, 0, 0);
}

// ---------------- init / graph build ----------------

__global__ void init_k(int* degi, int* cursor, float* scal,
                       float* ptW, float* ntW, float* svecraw, int* ecnt){
    int i = blockIdx.x*256 + threadIdx.x;
    if (i < NND){ degi[i]=0; cursor[i]=0; }
    if (i < 16) scal[i]=0.f;
    if (i == 0) ecnt[0]=0;
    if (i < 128) svecraw[i]=0.f;
    if (i < HH){ ptW[i]=0.f; ntW[i]=0.f; }
}

__global__ void count_k(const int* __restrict__ ei, int* degi){
    int i = blockIdx.x*256 + threadIdx.x;
    if (i < EE) atomicAdd(&degi[ei[EE + i]], 1);
}

__global__ void flag_k(const int* __restrict__ perm, const int* __restrict__ shuf,
                       int* flag, int* negsrc){
    int i = blockIdx.x*256 + threadIdx.x;
    if (i < NND){
        int p = perm[i];
        if (i < NM){ flag[p] = 1; negsrc[p] = -1; }
        else       { flag[p] = 0; negsrc[p] = perm[NM + shuf[i - NM]]; }
    }
}

// dinv + CSR segment allocation (order-free; per-block scan, 1 atomic/block)
__global__ __launch_bounds__(256) void alloc_k(const int* __restrict__ degi,
                                               float* dinv, int* rowptr, int* ecnt){
    __shared__ int sb[256];
    __shared__ int bbase;
    int t = threadIdx.x;
    int i = blockIdx.x*256 + t;
    int v = (i < NND) ? degi[i] : 0;
    sb[t] = v;
    __syncthreads();
    for (int off = 1; off < 256; off <<= 1){
        int x = 0;
        if (t >= off) x = sb[t - off];
        __syncthreads();
        sb[t] += x;
        __syncthreads();
    }
    if (t == 255) bbase = atomicAdd(ecnt, sb[255]);
    __syncthreads();
    if (i < NND){
        rowptr[i] = bbase + sb[t] - v;
        dinv[i] = 1.f/sqrtf((float)(degi[i] + 1));
    }
}

__global__ void fill_k(const int* __restrict__ ei, const int* __restrict__ rowptr,
                       int* cursor, int* adj){
    int i = blockIdx.x*256 + threadIdx.x;
    if (i < EE){
        int d = ei[EE + i];
        int s = ei[i];
        int p = atomicAdd(&cursor[d], 1);
        adj[rowptr[d] + p] = s;
    }
}

// token @ W1 partial sums
__global__ __launch_bounds__(512) void tok_k(const float* __restrict__ posT,
        const float* __restrict__ negT,
        const float* __restrict__ sW1, const float* __restrict__ tW1,
        float* ptW, float* ntW){
    int b = blockIdx.x; int chunk = blockIdx.y; int j = threadIdx.x;
    const float* tok = b ? negT : posT;
    const float* Wm  = b ? tW1  : sW1;
    float acc = 0.f;
    int d0 = chunk * (DD/8), d1 = d0 + (DD/8);
    for (int d = d0; d < d1; ++d) acc += tok[d] * Wm[(long)d*HH + j];
    atomicAdd(&((b ? ntW : ptW)[j]), acc);
}

// ---------------- casts for MFMA path ----------------

__global__ __launch_bounds__(256) void cast_pad_x_k(const float* __restrict__ x,
                                                    unsigned short* __restrict__ xb){
    long idx = (long)blockIdx.x*256 + threadIdx.x;
    if (idx >= (long)MP*(KP/8)) return;
    int row = (int)(idx / (KP/8));
    int g   = (int)(idx % (KP/8));
    unsigned short o[8] = {0,0,0,0,0,0,0,0};
    if (row < NND && g < DD/8){
        const float* src = x + (long)row*DD + g*8;
        float4 a = *(const float4*)(src);
        float4 b = *(const float4*)(src + 4);
        o[0]=f2b(a.x); o[1]=f2b(a.y); o[2]=f2b(a.z); o[3]=f2b(a.w);
        o[4]=f2b(b.x); o[5]=f2b(b.y); o[6]=f2b(b.z); o[7]=f2b(b.w);
    }
    *(uint4*)(xb + (long)row*KP + g*8) = *(const uint4*)o;
}

// batched transpose-cast: out[c*OS + r] = bf16(in[r*C + c]), zero-fill r in [R,OS)
struct TBatch {
    const float* in[10];
    unsigned short* out[10];
    int R[10], C[10], OS[10];
    int t0[11];
};

__global__ void transbatch_k(TBatch tb){
    __shared__ unsigned short tile[32][33];
    int b = blockIdx.x;
    int d = 0;
    while (d < 9 && b >= tb.t0[d+1]) d++;
    const float* in = tb.in[d];
    unsigned short* out = tb.out[d];
    int R = tb.R[d], C = tb.C[d], OS = tb.OS[d];
    int lt = b - tb.t0[d];
    int Ctiles = (C + 31) >> 5;
    int rt = lt / Ctiles, ct = lt % Ctiles;
    int rb = rt*32, cb = ct*32;
    int tx = threadIdx.x, ty = threadIdx.y; // (32,8)
    for (int i = ty; i < 32; i += 8){
        int r = rb + i, c = cb + tx;
        tile[i][tx] = (r < R && c < C) ? f2b(in[(long)r*C + c]) : (unsigned short)0;
    }
    __syncthreads();
    for (int i = ty; i < 32; i += 8){
        int c = cb + i, r = rb + tx;
        if (c < C && r < OS) out[(long)c*OS + r] = (r < R) ? tile[tx][i] : (unsigned short)0;
    }
}

// ---------------- 320x128 5-phase MFMA GEMM, 256 blocks (1/CU), bf16 out --------
// A: MP x KP bf16, Bg: NW x KP bf16 (row = output col). C guarded to M rows.
// A triple-buffered (3 x 40 KiB), B double-buffered (2 x 16 KiB) = 152 KiB LDS.
// Per K-tile: 5 phases; phase p computes m-tile p (4 nt x 2 ks = 8 MFMA).
// Staging per tile t: A(t+2) 1 gl_lds/phase/wave (5 total); B(t+2) at ph1,ph2.
// Gate: vmcnt(7) at ph4 (7 = this tile's in-flight loads) -> drains A(t+1),B(t+1).
// Swizzle (both-sides, rule 21): linear LDS dest; global source chunk pre-XOR'd
// with ((row>>3)&1)<<1; reads XOR the same involution. Zero bank conflicts (meas.).

#define LDA(PB, MT, KS) (*(const bf16x8*)&As[(PB) + (KS)*AH_STR + a_off + (MT)*512])
#define LDB(PB, NT, KS) (*(const bf16x8*)&Bs[(PB) + (KS)*BH_STR + b_off + (NT)*512])

#define STG_A(KT, PDST, P) gl_lds16(asrc[P] + ((KT)<<6), &As[(PDST) + adst[P]])
#define STG_B(KT, PDST, Q) gl_lds16(bsrc[Q] + ((KT)<<6), &Bs[(PDST) + bdst[Q]])

#define GATE7 asm volatile("s_waitcnt vmcnt(7)" ::: "memory")
#define GATE0 asm volatile("s_waitcnt vmcnt(0)" ::: "memory")
#define PIN   __builtin_amdgcn_sched_barrier(0)
#define NOOPS ((void)0)

// Phase P of a tile: ds-reads -> stage -> MFMA -> [gate] -> barrier -> [pin]
#define TPHASE(P, STAGE_STMT, GATE_STMT, PIN_STMT) {                             \
    bf16x8 a0 = LDA(pA, P, 0);                                                   \
    bf16x8 a1 = LDA(pA, P, 1);                                                   \
    if ((P) == 0){                                                               \
        _Pragma("unroll")                                                        \
        for (int nt = 0; nt < 4; ++nt){                                          \
            bfr[nt][0] = LDB(pB, nt, 0);                                         \
            bfr[nt][1] = LDB(pB, nt, 1);                                         \
        }                                                                        \
    }                                                                            \
    STAGE_STMT;                                                                  \
    __builtin_amdgcn_s_setprio(1);                                               \
    _Pragma("unroll")                                                            \
    for (int nt = 0; nt < 4; ++nt){                                              \
        acc[P][nt] = __builtin_amdgcn_mfma_f32_16x16x32_bf16(a0, bfr[nt][0], acc[P][nt], 0,0,0); \
        acc[P][nt] = __builtin_amdgcn_mfma_f32_16x16x32_bf16(a1, bfr[nt][1], acc[P][nt], 0,0,0); \
    }                                                                            \
    __builtin_amdgcn_s_setprio(0);                                               \
    GATE_STMT;                                                                   \
    __builtin_amdgcn_s_barrier();                                                \
    PIN_STMT;                                                                    \
}

__global__ __launch_bounds__(512, 2) void gemm320(
    const unsigned short* __restrict__ Ag,
    const unsigned short* __restrict__ Bg,
    unsigned short* __restrict__ C,
    int M, int Cstride)
{
    __shared__ __align__(1024) unsigned short As[3*AB_STR]; // 120 KiB
    __shared__ __align__(1024) unsigned short Bs[2*BB_STR]; //  32 KiB

    // bijective XCD-chunked swizzle (nwg = 256, 256 % 8 == 0)
    const int bid = blockIdx.x;
    const int swz = (bid & 7)*32 + (bid >> 3);
    const int m0 = (swz >> 3) * BMT;   // 32 m-tiles
    const int n0 = (swz & 7) * BNT;    // 8 n-tiles

    const int tid = threadIdx.x;
    const int w   = tid >> 6,  l = tid & 63;
    const int wm  = w >> 1,    wn = w & 1;      // 4(M) x 2(N) wave grid: 80x64/wave
    const int l16 = l & 15,    quad = l >> 4;

    // staging: lane l writes LDS row (g*16 + l>>2), physical chunk (l&3);
    // global source chunk pre-swizzled by row-bit3 = l bit5.
    const int schunk = (l & 3) ^ (((l >> 5) & 1) << 1);
    // reads: logical chunk 'quad' -> physical chunk quad ^ ((row>>3)&1)<<1, row bit3 = l16 bit3
    const int rq8   = ((quad ^ (((l16 >> 3) & 1) << 1)) << 3);
    const int a_off = ((wm*80 + l16) << 5) + rq8;
    const int b_off = ((wn*64 + l16) << 5) + rq8;

    // per-wave staging source pointers / LDS dest offsets (static-indexed)
    const unsigned short* asrc[5]; int adst[5];
    #pragma unroll
    for (int p = 0; p < 5; ++p){
        int j = 5*w + p, kh = j/20, g = j - kh*20;
        asrc[p] = Ag + (long)(m0 + g*16 + (l >> 2))*KP + (kh << 5) + (schunk << 3);
        adst[p] = kh*AH_STR + g*512;
    }
    const unsigned short* bsrc[2]; int bdst[2];
    #pragma unroll
    for (int q = 0; q < 2; ++q){
        int j = 2*w + q, kh = j >> 3, g = j & 7;
        bsrc[q] = Bg + (long)(n0 + g*16 + (l >> 2))*KP + (kh << 5) + (schunk << 3);
        bdst[q] = kh*BH_STR + g*512;
    }

    f32x4 acc[5][4];
    #pragma unroll
    for (int i = 0; i < 5; ++i)
        #pragma unroll
        for (int j = 0; j < 4; ++j)
            #pragma unroll
            for (int r = 0; r < 4; ++r) acc[i][j][r] = 0.f;

    bf16x8 bfr[4][2];

    // prologue: A(0)->ab0, B(0)->bb0, A(1)->ab1, B(1)->bb1; full drain.
    #pragma unroll
    for (int p = 0; p < 5; ++p) STG_A(0, 0, p);
    #pragma unroll
    for (int q = 0; q < 2; ++q) STG_B(0, 0, q);
    #pragma unroll
    for (int p = 0; p < 5; ++p) STG_A(1, AB_STR, p);
    #pragma unroll
    for (int q = 0; q < 2; ++q) STG_B(1, BB_STR, q);
    GATE0;
    __builtin_amdgcn_s_barrier();
    PIN;

    int ab = 0, bb = 0;   // buf of tile t: ab = t%3, bb = t&1
    #pragma unroll 1
    for (int t = 0; t < KTILES-2; ++t){
        const int pA  = ab*AB_STR;
        const int ab2 = (ab == 0) ? 2 : ab - 1;      // (t+2)%3
        const int pA2 = ab2*AB_STR;
        const int pB  = bb*BB_STR;                   // B(t) buf == B(t+2) dest buf
        TPHASE(0, STG_A(t+2, pA2, 0),                        NOOPS, PIN)
        TPHASE(1, { STG_A(t+2, pA2, 1); STG_B(t+2, pB, 0); }, NOOPS, NOOPS)
        TPHASE(2, { STG_A(t+2, pA2, 2); STG_B(t+2, pB, 1); }, NOOPS, NOOPS)
        TPHASE(3, STG_A(t+2, pA2, 3),                        NOOPS, NOOPS)
        TPHASE(4, STG_A(t+2, pA2, 4),                        GATE7, PIN)
        ab = (ab == 2) ? 0 : ab + 1;
        bb ^= 1;
    }
    // peeled tile KTILES-2 (no staging; full drain for last tile's data)
    {
        const int pA = ab*AB_STR, pB = bb*BB_STR;
        TPHASE(0, NOOPS, NOOPS, NOOPS)
        TPHASE(1, NOOPS, NOOPS, NOOPS)
        TPHASE(2, NOOPS, NOOPS, NOOPS)
        TPHASE(3, NOOPS, NOOPS, NOOPS)
        TPHASE(4, NOOPS, GATE0, PIN)
        ab = (ab == 2) ? 0 : ab + 1;
        bb ^= 1;
    }
    // peeled tile KTILES-1 (no staging, no gate)
    {
        const int pA = ab*AB_STR, pB = bb*BB_STR;
        TPHASE(0, NOOPS, NOOPS, NOOPS)
        TPHASE(1, NOOPS, NOOPS, NOOPS)
        TPHASE(2, NOOPS, NOOPS, NOOPS)
        TPHASE(3, NOOPS, NOOPS, NOOPS)
        TPHASE(4, NOOPS, NOOPS, NOOPS)
    }

    // epilogue: C/D layout col=lane&15, row=quad*4+reg
    #pragma unroll
    for (int mt = 0; mt < 5; ++mt){
        const int rowb = m0 + wm*80 + mt*16 + quad*4;
        #pragma unroll
        for (int nt = 0; nt < 4; ++nt){
            const int col = n0 + wn*64 + nt*16 + l16;
            #pragma unroll
            for (int r = 0; r < 4; ++r){
                const int row = rowb + r;
                if (row < M) C[(long)row*Cstride + col] = f2b(acc[mt][nt][r]);
            }
        }
    }
}

// ---------------- 64x64 MFMA GEMM: C = A[ridx?] @ BT^T (+epi) ----------------
// A: MxK bf16, BT: NnxK bf16, K % 32 == 0. epi: 0 none, 1 +bias, 2 +bias+prelu.
// obf: output bf16 (else f32). ridx: optional A row gather.
__global__ __launch_bounds__(256) void gemm_bt_ex(
    const unsigned short* __restrict__ A,
    const unsigned short* __restrict__ BT,
    void* __restrict__ Cv,
    int M, int Nn, int K, int Cstride,
    const float* __restrict__ bias,
    const float* __restrict__ alpha,
    int epi, const int* __restrict__ ridx, int obf)
{
    __shared__ __align__(16) unsigned short As[64*40];
    __shared__ __align__(16) unsigned short Bs[64*40];
    const int m0 = blockIdx.y*64, n0 = blockIdx.x*64;
    const int t = threadIdx.x;
    const int lrow = t >> 2, lk = (t & 3) * 8;
    const int wave = t >> 6, lane = t & 63;
    const int quad = lane >> 4, l16 = lane & 15;
    f32x4 acc[4];
    #pragma unroll
    for (int i = 0; i < 4; i++)
        for (int j = 0; j < 4; j++) acc[i][j] = 0.f;

    const bool arv = (m0 + lrow) < M;
    const bool brv = (n0 + lrow) < Nn;
    long arow = 0;
    if (arv) arow = ridx ? (long)ridx[m0 + lrow] : (long)(m0 + lrow);
    const long arowbase = arow * K;
    const long browbase = (long)(n0 + lrow) * K;

    for (int k0 = 0; k0 < K; k0 += 32){
        int gk = k0 + lk;
        uint4 av = {0u,0u,0u,0u};
        uint4 bv = {0u,0u,0u,0u};
        if (arv) av = *(const uint4*)(A + arowbase + gk);
        if (brv) bv = *(const uint4*)(BT + browbase + gk);
        *(uint4*)(&As[lrow*40 + lk]) = av;
        *(uint4*)(&Bs[lrow*40 + lk]) = bv;
        __syncthreads();
        bf16x8 af = *(const bf16x8*)(&As[(wave*16 + l16)*40 + quad*8]);
        #pragma unroll
        for (int nt = 0; nt < 4; nt++){
            bf16x8 bfr = *(const bf16x8*)(&Bs[(nt*16 + l16)*40 + quad*8]);
            acc[nt] = __builtin_amdgcn_mfma_f32_16x16x32_bf16(af, bfr, acc[nt], 0, 0, 0);
        }
        __syncthreads();
    }

    const int rowb = m0 + wave*16 + quad*4;
    float aval = (epi == 2) ? alpha[0] : 0.f;
    #pragma unroll
    for (int nt = 0; nt < 4; nt++){
        int col = n0 + nt*16 + l16;
        if (col >= Nn) continue;
        float bvv = epi ? bias[col] : 0.f;
        #pragma unroll
        for (int r = 0; r < 4; r++){
            int row = rowb + r;
            if (row < M){
                float v = acc[nt][r] + bvv;
                if (epi == 2 && v < 0.f) v *= aval;
                if (obf) ((unsigned short*)Cv)[(long)row*Cstride + col] = f2b(v);
                else     ((float*)Cv)[(long)row*Cstride + col] = v;
            }
        }
    }
}

// ---------------- fused GCN layer-1 aggregation (pos + neg), bf16 I/O ----------------

__global__ __launch_bounds__(256) void agg1_k(const unsigned short* __restrict__ XW,
    const float* __restrict__ ptW, const float* __restrict__ ntW,
    const int* __restrict__ flag, const int* __restrict__ negsrc,
    const float* __restrict__ dinv, const int* __restrict__ rowptr,
    const int* __restrict__ degi, const int* __restrict__ adj,
    const float* __restrict__ sb1, const float* __restrict__ sav,
    const float* __restrict__ tb1, const float* __restrict__ tav,
    unsigned short* __restrict__ H1p, unsigned short* __restrict__ H1n)
{
    int i = blockIdx.x; int t = threadIdx.x;
    int c = 2*t;                       // cols c, c+1 in [0,512)
    float di = dinv[i];
    int rs = rowptr[i], re = rs + degi[i];
    float p0 = ptW[c], p1 = ptW[c+1];
    float n0v = ntW[c], n1v = ntW[c+1];
    int fi = flag[i];
    int nsi = negsrc[i]; if (nsi < 0) nsi = 0;
    float ffi = fi ? 1.f : 0.f;
    float2 xp = bpair(*(const unsigned int*)(XW + (long)i*1024 + c));
    float2 xn = bpair(*(const unsigned int*)(XW + (long)nsi*1024 + 512 + c));
    float pa0 = (xp.x + ffi*p0) * di;
    float pa1 = (xp.y + ffi*p1) * di;
    float na0 = (fi ? n0v : xn.x) * di;
    float na1 = (fi ? n1v : xn.y) * di;
    for (int e = rs; e < re; ++e){
        int s = adj[e]; float ds = dinv[s];
        int fs = flag[s];
        int ns = negsrc[s]; if (ns < 0) ns = 0;
        float ffs = fs ? 1.f : 0.f;
        float2 sp = bpair(*(const unsigned int*)(XW + (long)s*1024 + c));
        float2 sn = bpair(*(const unsigned int*)(XW + (long)ns*1024 + 512 + c));
        pa0 += (sp.x + ffs*p0) * ds;
        pa1 += (sp.y + ffs*p1) * ds;
        na0 += (fs ? n0v : sn.x) * ds;
        na1 += (fs ? n1v : sn.y) * ds;
    }
    float sa_ = sav[0], ta_ = tav[0];
    float v0 = di*pa0 + sb1[c];   if (v0 < 0.f) v0 *= sa_;
    float v1 = di*pa1 + sb1[c+1]; if (v1 < 0.f) v1 *= sa_;
    float w0 = di*na0 + tb1[c];   if (w0 < 0.f) w0 *= ta_;
    float w1 = di*na1 + tb1[c+1]; if (w1 < 0.f) w1 *= ta_;
    *(unsigned int*)(H1p + (long)i*512 + c) = packb(v0, v1);
    *(unsigned int*)(H1n + (long)i*512 + c) = packb(w0, w1);
}

__global__ __launch_bounds__(128) void agg128_k(const unsigned short* __restrict__ In,
    const float* __restrict__ dinv, const int* __restrict__ rowptr,
    const int* __restrict__ degi, const int* __restrict__ adj,
    const float* __restrict__ b2, const float* __restrict__ a2,
    unsigned short* __restrict__ Out)
{
    int i = blockIdx.x, t = threadIdx.x;
    float di = dinv[i];
    int rs = rowptr[i], re = rs + degi[i];
    float acc = b2f(In[(long)i*128 + t]) * di;
    for (int e = rs; e < re; ++e){
        int s = adj[e];
        acc += b2f(In[(long)s*128 + t]) * dinv[s];
    }
    float v = di*acc + b2[t];
    float a = a2[0]; if (v < 0.f) v *= a;
    Out[(long)i*128 + t] = f2b(v);
}

__global__ __launch_bounds__(128) void aggrec_k(const unsigned short* __restrict__ recPre,
    const float* __restrict__ dinv, const int* __restrict__ rowptr,
    const int* __restrict__ degi, const int* __restrict__ adj,
    const int* __restrict__ flag, const int* __restrict__ perm,
    unsigned short* __restrict__ recAgg)
{
    int b = blockIdx.x, t = threadIdx.x;
    int i = perm[b];
    float di = dinv[i];
    int rs = rowptr[i], re = rs + degi[i];
    float acc = 0.f; // self loop: i is a mask node -> rec row zeroed
    for (int e = rs; e < re; ++e){
        int s = adj[e];
        if (!flag[s]) acc += b2f(recPre[(long)s*128 + t]) * dinv[s];
    }
    recAgg[(long)b*128 + t] = f2b(di * acc);
}

// ---------------- DGI head ----------------

__global__ __launch_bounds__(128) void meanp_k(const float* __restrict__ posZ,
                                               float* svecraw){
    int j = threadIdx.x;
    int r0 = blockIdx.x*64, r1 = r0 + 64; if (r1 > NM) r1 = NM;
    float s = 0.f;
    for (int r = r0; r < r1; ++r) s += posZ[(long)r*128 + j];
    atomicAdd(&svecraw[j], s);
}

__global__ void ws_k(const float* __restrict__ dgiW, const float* __restrict__ svecraw,
                     float* wsv){
    __shared__ float s[128];
    int i = threadIdx.x; // 128
    s[i] = 1.f/(1.f + expf(-svecraw[i]/(float)NM));
    __syncthreads();
    float a = 0.f;
    for (int j = 0; j < 128; ++j) a += dgiW[i*128 + j] * s[j];
    wsv[i] = a;
}

__global__ __launch_bounds__(256) void dgi_k(const float* __restrict__ posZ,
    const float* __restrict__ negZ, const float* __restrict__ wsv, float* scal){
    int row = blockIdx.x*4 + (threadIdx.x >> 6);
    int lane = threadIdx.x & 63;
    if (row >= 2*NM) return;
    const float* Z = (row < NM) ? posZ : negZ;
    int r = (row < NM) ? row : row - NM;
    float v = Z[(long)r*128 + lane] * wsv[lane]
            + Z[(long)r*128 + 64 + lane] * wsv[64 + lane];
    for (int off = 32; off; off >>= 1) v += __shfl_down(v, off, 64);
    if (lane == 0){
        float d = 1.f/(1.f + expf(-v));
        float lg = (row < NM) ? logf(d + 1e-15f) : logf(1.f - d + 1e-15f);
        atomicAdd(&scal[(row < NM) ? 0 : 1], lg);
    }
}

// ---------------- cosine feature loss ----------------

__global__ __launch_bounds__(256) void cos_k(const float* __restrict__ x,
    const unsigned short* __restrict__ recMask, const int* __restrict__ perm,
    float* scal){
    int b = blockIdx.x, t = threadIdx.x;
    long xi = (long)perm[b]*DD;
    long ri = (long)b*DD;
    float dot = 0.f, nx = 0.f, nr = 0.f;
    for (int d = t; d < DD; d += 256){
        float xv = x[xi + d], rv = b2f(recMask[ri + d]);
        dot += xv*rv; nx += xv*xv; nr += rv*rv;
    }
    for (int off = 32; off; off >>= 1){
        dot += __shfl_down(dot, off, 64);
        nx  += __shfl_down(nx,  off, 64);
        nr  += __shfl_down(nr,  off, 64);
    }
    __shared__ float sd[4], sx[4], sr[4];
    int w = t >> 6, lane = t & 63;
    if (lane == 0){ sd[w] = dot; sx[w] = nx; sr[w] = nr; }
    __syncthreads();
    if (t == 0){
        float Dv = sd[0]+sd[1]+sd[2]+sd[3];
        float Xv = sx[0]+sx[1]+sx[2]+sx[3];
        float Rv = sr[0]+sr[1]+sr[2]+sr[3];
        float c = Dv/(fmaxf(sqrtf(Xv),1e-12f)*fmaxf(sqrtf(Rv),1e-12f));
        float e = 1.f - c;
        atomicAdd(&scal[2], e*e);
    }
}

__global__ void fin_k(const float* __restrict__ scal, float* out){
    float feat = scal[2]/(float)NM;
    float dgi  = -(scal[0]/(float)NM) - (scal[1]/(float)NM);
    out[0] = feat;
    out[1] = dgi;
}

// ---------------- launch ----------------

extern "C" void kernel_launch(void* const* d_in, const int* in_sizes, int n_in,
                              void* d_out, int out_size, void* d_ws, size_t ws_size,
                              hipStream_t stream) {
    (void)in_sizes; (void)n_in; (void)out_size; (void)d_ws; (void)ws_size;
    const float* x  = (const float*)d_in[0];
    const int* ei   = (const int*)d_in[1];
    const int* perm = (const int*)d_in[2];
    const int* shuf = (const int*)d_in[3];
    const float* sW1 = (const float*)d_in[4];
    const float* sb1 = (const float*)d_in[5];
    const float* sa  = (const float*)d_in[6];
    const float* sW2 = (const float*)d_in[7];
    const float* sb2 = (const float*)d_in[8];
    const float* tW1 = (const float*)d_in[9];
    const float* tb1 = (const float*)d_in[10];
    const float* ta  = (const float*)d_in[11];
    const float* tW2 = (const float*)d_in[12];
    const float* tb2 = (const float*)d_in[13];
    const float* pW1 = (const float*)d_in[14];
    const float* pb1 = (const float*)d_in[15];
    const float* pa  = (const float*)d_in[16];
    const float* pW2 = (const float*)d_in[17];
    const float* pb2 = (const float*)d_in[18];
    const float* tpW1 = (const float*)d_in[19];
    const float* tpb1 = (const float*)d_in[20];
    const float* tpa  = (const float*)d_in[21];
    const float* tpW2 = (const float*)d_in[22];
    const float* tpb2 = (const float*)d_in[23];
    const float* dgiW = (const float*)d_in[24];
    const float* posT = (const float*)d_in[25];
    const float* negT = (const float*)d_in[26];
    const float* e2dW = (const float*)d_in[27];
    const float* dW   = (const float*)d_in[28];
    const float* db   = (const float*)d_in[29];
    float* out = (float*)d_out;

    void* wsp = nullptr;
    hipGetSymbolAddress(&wsp, HIP_SYMBOL(g_ws));
    char* base = (char*)wsp;
    size_t off = 0;
    auto alloc = [&](size_t b){ size_t o = off; off = (off + b + 255) & ~(size_t)255; return o; };

    float* dinv    = (float*)(base + alloc(NND*4));
    int* degi      = (int*)  (base + alloc(NND*4));
    int* rowptr    = (int*)  (base + alloc(NND*4));
    int* cursor    = (int*)  (base + alloc(NND*4));
    int* adj       = (int*)  (base + alloc(EE*4));
    int* flag      = (int*)  (base + alloc(NND*4));
    int* negsrc    = (int*)  (base + alloc(NND*4));
    int* ecnt      = (int*)  (base + alloc(16*4));
    float* ptW     = (float*)(base + alloc(HH*4));
    float* ntW     = (float*)(base + alloc(HH*4));
    float* svecraw = (float*)(base + alloc(128*4));
    float* wsv     = (float*)(base + alloc(128*4));
    float* scal    = (float*)(base + alloc(16*4));

    unsigned short* xb    = (unsigned short*)(base + alloc((size_t)MP*KP*2));
    unsigned short* W1T   = (unsigned short*)(base + alloc((size_t)NW*KP*2));
    unsigned short* sW2T  = (unsigned short*)(base + alloc((size_t)LL*HH*2));
    unsigned short* tW2T  = (unsigned short*)(base + alloc((size_t)LL*HH*2));
    unsigned short* pW1T  = (unsigned short*)(base + alloc((size_t)PP*LL*2));
    unsigned short* pW2T  = (unsigned short*)(base + alloc((size_t)LL*PP*2));
    unsigned short* tpW1T = (unsigned short*)(base + alloc((size_t)PP*LL*2));
    unsigned short* tpW2T = (unsigned short*)(base + alloc((size_t)LL*PP*2));
    unsigned short* e2dWT = (unsigned short*)(base + alloc((size_t)LL*LL*2));
    unsigned short* dWT   = (unsigned short*)(base + alloc((size_t)DD*LL*2));

    unsigned short* XW      = (unsigned short*)(base + alloc((size_t)NND*1024*2));
    unsigned short* H1p     = (unsigned short*)(base + alloc((size_t)NND*512*2));
    unsigned short* H1n     = (unsigned short*)(base + alloc((size_t)NND*512*2));
    unsigned short* M2p     = (unsigned short*)(base + alloc((size_t)NND*128*2));
    unsigned short* M2n     = (unsigned short*)(base + alloc((size_t)NND*128*2));
    unsigned short* repP    = (unsigned short*)(base + alloc((size_t)NND*128*2));
    unsigned short* repN    = (unsigned short*)(base + alloc((size_t)NND*128*2));
    unsigned short* posH    = (unsigned short*)(base + alloc((size_t)NM*256*2));
    unsigned short* negH    = (unsigned short*)(base + alloc((size_t)NM*256*2));
    float* posZ             = (float*)(base + alloc((size_t)NM*128*4));
    float* negZ             = (float*)(base + alloc((size_t)NM*128*4));
    unsigned short* recPre  = (unsigned short*)(base + alloc((size_t)NND*128*2));
    unsigned short* recAgg  = (unsigned short*)(base + alloc((size_t)NM*128*2));
    unsigned short* recMask = (unsigned short*)(base + alloc((size_t)NM*DD*2));

    // ---- graph build (scan-free) ----
    init_k<<<(NND+255)/256, 256, 0, stream>>>(degi, cursor, scal, ptW, ntW, svecraw, ecnt);
    flag_k<<<(NND+255)/256, 256, 0, stream>>>(perm, shuf, flag, negsrc);
    count_k<<<(EE+255)/256, 256, 0, stream>>>(ei, degi);
    alloc_k<<<(NND+255)/256, 256, 0, stream>>>(degi, dinv, rowptr, ecnt);
    fill_k<<<(EE+255)/256, 256, 0, stream>>>(ei, rowptr, cursor, adj);
    tok_k<<<dim3(2,8), 512, 0, stream>>>(posT, negT, sW1, tW1, ptW, ntW);

    // ---- bf16 staging ----
    cast_pad_x_k<<<(int)(((long)MP*(KP/8) + 255)/256), 256, 0, stream>>>(x, xb);
    {
        TBatch tb;
        const float* ins[10] = {sW1, tW1, sW2, tW2, pW1, pW2, tpW1, tpW2, e2dW, dW};
        unsigned short* outs[10] = {W1T, W1T + (size_t)HH*KP, sW2T, tW2T, pW1T, pW2T,
                                    tpW1T, tpW2T, e2dWT, dWT};
        int Rs[10]  = {DD, DD, HH, HH, LL, PP, LL, PP, LL, LL};
        int Cs[10]  = {HH, HH, LL, LL, PP, LL, PP, LL, LL, DD};
        int OSs[10] = {KP, KP, HH, HH, LL, PP, LL, PP, LL, LL};
        int cum = 0;
        for (int d = 0; d < 10; d++){
            tb.in[d] = ins[d]; tb.out[d] = outs[d];
            tb.R[d] = Rs[d]; tb.C[d] = Cs[d]; tb.OS[d] = OSs[d];
            tb.t0[d] = cum;
            cum += (OSs[d]/32) * ((Cs[d] + 31)/32);
        }
        tb.t0[10] = cum;
        transbatch_k<<<cum, dim3(32,8), 0, stream>>>(tb);
    }

    // ---- encoder layer 1 (MFMA 320x128 5-phase, 256 blocks) + fused aggregation ----
    gemm320<<<256, 512, 0, stream>>>(xb, W1T, XW, NND, 1024);
    agg1_k<<<NND, 256, 0, stream>>>(XW, ptW, ntW, flag, negsrc, dinv, rowptr, degi, adj,
                                    sb1, sa, tb1, ta, H1p, H1n);

    // ---- encoder layer 2 (MFMA) ----
    gemm_bt_ex<<<dim3(2,157), 256, 0, stream>>>(H1p, sW2T, M2p, NND, LL, HH, LL,
                                                nullptr, nullptr, 0, nullptr, 1);
    gemm_bt_ex<<<dim3(2,157), 256, 0, stream>>>(H1n, tW2T, M2n, NND, LL, HH, LL,
                                                nullptr, nullptr, 0, nullptr, 1);
    agg128_k<<<NND, 128, 0, stream>>>(M2p, dinv, rowptr, degi, adj, sb2, sa, repP);
    agg128_k<<<NND, 128, 0, stream>>>(M2n, dinv, rowptr, degi, adj, tb2, ta, repN);

    // ---- projections on mask rows (MFMA, gathered A via perm) ----
    gemm_bt_ex<<<dim3(4,47), 256, 0, stream>>>(repP, pW1T, posH, NM, PP, LL, PP,
                                               pb1, pa, 2, perm, 1);
    gemm_bt_ex<<<dim3(2,47), 256, 0, stream>>>(posH, pW2T, posZ, NM, LL, PP, LL,
                                               pb2, nullptr, 1, nullptr, 0);
    gemm_bt_ex<<<dim3(4,47), 256, 0, stream>>>(repN, tpW1T, negH, NM, PP, LL, PP,
                                               tpb1, tpa, 2, perm, 1);
    gemm_bt_ex<<<dim3(2,47), 256, 0, stream>>>(negH, tpW2T, negZ, NM, LL, PP, LL,
                                               tpb2, nullptr, 1, nullptr, 0);

    // ---- DGI loss ----
    meanp_k<<<47, 128, 0, stream>>>(posZ, svecraw);
    ws_k<<<1, 128, 0, stream>>>(dgiW, svecraw, wsv);
    dgi_k<<<(2*NM)/4, 256, 0, stream>>>(posZ, negZ, wsv, scal);

    // ---- decoder + feature loss (MFMA) ----
    gemm_bt_ex<<<dim3(2,157), 256, 0, stream>>>(repP, e2dWT, recPre, NND, LL, LL, LL,
                                                nullptr, nullptr, 0, nullptr, 1);
    aggrec_k<<<NM, 128, 0, stream>>>(recPre, dinv, rowptr, degi, adj, flag, perm, recAgg);
    gemm_bt_ex<<<dim3(47,47), 256, 0, stream>>>(recAgg, dWT, recMask, NM, DD, LL, DD,
                                                db, nullptr, 1, nullptr, 1);
    cos_k<<<NM, 256, 0, stream>>>(x, recMask, perm, scal);

    fin_k<<<1, 1, 0, stream>>>(scal, out);
}

// Round 3
// 613.487 us; speedup vs baseline: 1.1158x; 1.0748x over previous
//
#include <hip/hip_runtime.h>

#define NND 10000
#define EE  60000
#define DD  3000
#define HH  512
#define LL  128
#define PP  256
#define NM  3000

// padded dims for the big MFMA GEMM (no tail guards in hot loop)
#define KP  3072            // 48 * 64
#define MP  10240           // 32 * 320
#define NW  1024            // [sW1|tW1] fused width, 8*128
#define KTILES (KP/64)      // 48

// gemm320 tile geometry
#define BMT 320
#define BNT 128
#define AH_STR 10240        // elems per A k-half (320 rows x 32)
#define AB_STR 20480        // elems per A buf (2 k-halves)
#define BH_STR 4096         // elems per B k-half (128 rows x 32)
#define BB_STR 8192         // elems per B buf

typedef short bf16x8 __attribute__((ext_vector_type(8)));
typedef float f32x4 __attribute__((ext_vector_type(4)));

// All scratch lives in module BSS -> no dependency on harness ws_size.
__device__ __align__(256) char g_ws[(size_t)176 << 20];

__device__ __forceinline__ unsigned short f2b(float f){
    unsigned int x = __float_as_uint(f);
    unsigned int r = x + 0x7FFFu + ((x >> 16) & 1u);
    return (unsigned short)(r >> 16);
}
__device__ __forceinline__ float b2f(unsigned short u){
    return __uint_as_float(((unsigned int)u) << 16);
}
// uint holding 2 bf16 (low = col c, high = col c+1)
__device__ __forceinline__ float2 bpair(unsigned int u){
    float2 r;
    r.x = __uint_as_float(u << 16);
    r.y = __uint_as_float(u & 0xffff0000u);
    return r;
}
__device__ __forceinline__ unsigned int packb(float a, float b){
    return (unsigned int)f2b(a) | ((unsigned int)f2b(b) << 16);
}

__device__ __forceinline__ void gl_lds16(const void* g, void* l){
    __builtin_amdgcn_global_load_lds(
        (const __attribute__((address_space(1))) unsigned int*)g,
        (__attribute__((address_space(3))) unsigned int*)l, 16, 0, 0);
}

// ---------------- init / graph build ----------------

__global__ void init_k(int* degi, int* cursor, float* scal,
                       float* ptW, float* ntW, float* svecraw, int* ecnt){
    int i = blockIdx.x*256 + threadIdx.x;
    if (i < NND){ degi[i]=0; cursor[i]=0; }
    if (i < 16) scal[i]=0.f;
    if (i == 0) ecnt[0]=0;
    if (i < 128) svecraw[i]=0.f;
    if (i < HH){ ptW[i]=0.f; ntW[i]=0.f; }
}

__global__ void count_k(const int* __restrict__ ei, int* degi){
    int i = blockIdx.x*256 + threadIdx.x;
    if (i < EE) atomicAdd(&degi[ei[EE + i]], 1);
}

__global__ void flag_k(const int* __restrict__ perm, const int* __restrict__ shuf,
                       int* flag, int* negsrc){
    int i = blockIdx.x*256 + threadIdx.x;
    if (i < NND){
        int p = perm[i];
        if (i < NM){ flag[p] = 1; negsrc[p] = -1; }
        else       { flag[p] = 0; negsrc[p] = perm[NM + shuf[i - NM]]; }
    }
}

// dinv + CSR segment allocation (order-free; per-block scan, 1 atomic/block)
__global__ __launch_bounds__(256) void alloc_k(const int* __restrict__ degi,
                                               float* dinv, int* rowptr, int* ecnt){
    __shared__ int sb[256];
    __shared__ int bbase;
    int t = threadIdx.x;
    int i = blockIdx.x*256 + t;
    int v = (i < NND) ? degi[i] : 0;
    sb[t] = v;
    __syncthreads();
    for (int off = 1; off < 256; off <<= 1){
        int x = 0;
        if (t >= off) x = sb[t - off];
        __syncthreads();
        sb[t] += x;
        __syncthreads();
    }
    if (t == 255) bbase = atomicAdd(ecnt, sb[255]);
    __syncthreads();
    if (i < NND){
        rowptr[i] = bbase + sb[t] - v;
        dinv[i] = 1.f/sqrtf((float)(degi[i] + 1));
    }
}

__global__ void fill_k(const int* __restrict__ ei, const int* __restrict__ rowptr,
                       int* cursor, int* adj){
    int i = blockIdx.x*256 + threadIdx.x;
    if (i < EE){
        int d = ei[EE + i];
        int s = ei[i];
        int p = atomicAdd(&cursor[d], 1);
        adj[rowptr[d] + p] = s;
    }
}

// token @ W1 partial sums
__global__ __launch_bounds__(512) void tok_k(const float* __restrict__ posT,
        const float* __restrict__ negT,
        const float* __restrict__ sW1, const float* __restrict__ tW1,
        float* ptW, float* ntW){
    int b = blockIdx.x; int chunk = blockIdx.y; int j = threadIdx.x;
    const float* tok = b ? negT : posT;
    const float* Wm  = b ? tW1  : sW1;
    float acc = 0.f;
    int d0 = chunk * (DD/8), d1 = d0 + (DD/8);
    for (int d = d0; d < d1; ++d) acc += tok[d] * Wm[(long)d*HH + j];
    atomicAdd(&((b ? ntW : ptW)[j]), acc);
}

// ---------------- casts for MFMA path ----------------

__global__ __launch_bounds__(256) void cast_pad_x_k(const float* __restrict__ x,
                                                    unsigned short* __restrict__ xb){
    long idx = (long)blockIdx.x*256 + threadIdx.x;
    if (idx >= (long)MP*(KP/8)) return;
    int row = (int)(idx / (KP/8));
    int g   = (int)(idx % (KP/8));
    unsigned short o[8] = {0,0,0,0,0,0,0,0};
    if (row < NND && g < DD/8){
        const float* src = x + (long)row*DD + g*8;
        float4 a = *(const float4*)(src);
        float4 b = *(const float4*)(src + 4);
        o[0]=f2b(a.x); o[1]=f2b(a.y); o[2]=f2b(a.z); o[3]=f2b(a.w);
        o[4]=f2b(b.x); o[5]=f2b(b.y); o[6]=f2b(b.z); o[7]=f2b(b.w);
    }
    *(uint4*)(xb + (long)row*KP + g*8) = *(const uint4*)o;
}

// batched transpose-cast: out[c*OS + r] = bf16(in[r*C + c]), zero-fill r in [R,OS)
struct TBatch {
    const float* in[10];
    unsigned short* out[10];
    int R[10], C[10], OS[10];
    int t0[11];
};

__global__ void transbatch_k(TBatch tb){
    __shared__ unsigned short tile[32][33];
    int b = blockIdx.x;
    int d = 0;
    while (d < 9 && b >= tb.t0[d+1]) d++;
    const float* in = tb.in[d];
    unsigned short* out = tb.out[d];
    int R = tb.R[d], C = tb.C[d], OS = tb.OS[d];
    int lt = b - tb.t0[d];
    int Ctiles = (C + 31) >> 5;
    int rt = lt / Ctiles, ct = lt % Ctiles;
    int rb = rt*32, cb = ct*32;
    int tx = threadIdx.x, ty = threadIdx.y; // (32,8)
    for (int i = ty; i < 32; i += 8){
        int r = rb + i, c = cb + tx;
        tile[i][tx] = (r < R && c < C) ? f2b(in[(long)r*C + c]) : (unsigned short)0;
    }
    __syncthreads();
    for (int i = ty; i < 32; i += 8){
        int c = cb + i, r = rb + tx;
        if (c < C && r < OS) out[(long)c*OS + r] = (r < R) ? tile[tx][i] : (unsigned short)0;
    }
}

// ---------------- 320x128 MFMA GEMM, 256 blocks (1/CU), 3-barrier tiles --------
// A: MP x KP bf16, Bg: NW x KP bf16 (row = output col). C guarded to M rows.
// A triple-buffered (3 x 40 KiB), B double-buffered (2 x 16 KiB) = 152 KiB LDS.
// Per K-tile: [18 frag ds_reads + 4 A-prefetch gl_lds] BAR [16 MFMA mt0-1] BAR
//             [1 A + 2 B gl_lds] [24 MFMA mt2-4] vmcnt(7) BAR.
// Reads are issued BEFORE the rendezvous so the barrier absorbs LDS latency;
// compiler inserts counted lgkmcnt before each dependent MFMA (no asm wall).
// Hazards: A(t+2) buf is distinct from A(t),A(t+1) (triple buffer) -> safe at
// phase 1. B(t+2) overwrites B(t)'s buffer -> issued only after BAR2 (all
// waves' B reads complete). Gate vmcnt(7) + BAR3 drains tile t-1's 7 loads
// before tile t+1 reads them (per-wave vmcnt + rendezvous = global drain).
// Swizzle (both-sides, rule 21): linear LDS dest; global source chunk pre-XOR'd
// with ((row>>3)&1)<<1; reads XOR the same involution. Zero bank conflicts (meas.).

#define LDA(PB, MT, KS) (*(const bf16x8*)&As[(PB) + (KS)*AH_STR + a_off + (MT)*512])
#define LDB(PB, NT, KS) (*(const bf16x8*)&Bs[(PB) + (KS)*BH_STR + b_off + (NT)*512])

#define STG_A(KT, PDST, P) gl_lds16(asrc[P] + ((KT)<<6), &As[(PDST) + adst[P]])
#define STG_B(KT, PDST, Q) gl_lds16(bsrc[Q] + ((KT)<<6), &Bs[(PDST) + bdst[Q]])

#define GATE7 asm volatile("s_waitcnt vmcnt(7)" ::: "memory")
#define GATE0 asm volatile("s_waitcnt vmcnt(0)" ::: "memory")
#define NOOPS ((void)0)
#define AFENCE asm volatile("" ::: "memory")
#define BARR  { AFENCE; __builtin_amdgcn_s_barrier(); AFENCE; }

#define TILE_BODY(S1_STMT, S2_STMT, GATE_STMT) {                                  \
    bf16x8 af_[5][2], bf_[4][2];                                                  \
    _Pragma("unroll") for (int nt = 0; nt < 4; ++nt){                             \
        bf_[nt][0] = LDB(pB, nt, 0); bf_[nt][1] = LDB(pB, nt, 1); }               \
    _Pragma("unroll") for (int mt = 0; mt < 5; ++mt){                             \
        af_[mt][0] = LDA(pA, mt, 0); af_[mt][1] = LDA(pA, mt, 1); }               \
    S1_STMT;                                                                      \
    BARR;                                                                         \
    __builtin_amdgcn_s_setprio(1);                                                \
    _Pragma("unroll") for (int ks = 0; ks < 2; ++ks)                              \
      _Pragma("unroll") for (int nt = 0; nt < 4; ++nt)                            \
        _Pragma("unroll") for (int mt = 0; mt < 2; ++mt)                          \
          acc[mt][nt] = __builtin_amdgcn_mfma_f32_16x16x32_bf16(af_[mt][ks], bf_[nt][ks], acc[mt][nt], 0,0,0); \
    __builtin_amdgcn_s_setprio(0);                                                \
    BARR;                                                                         \
    S2_STMT;                                                                      \
    __builtin_amdgcn_s_setprio(1);                                                \
    _Pragma("unroll") for (int ks = 0; ks < 2; ++ks)                              \
      _Pragma("unroll") for (int nt = 0; nt < 4; ++nt)                            \
        _Pragma("unroll") for (int mt = 2; mt < 5; ++mt)                          \
          acc[mt][nt] = __builtin_amdgcn_mfma_f32_16x16x32_bf16(af_[mt][ks], bf_[nt][ks], acc[mt][nt], 0,0,0); \
    __builtin_amdgcn_s_setprio(0);                                                \
    GATE_STMT;                                                                    \
    BARR;                                                                         \
}

__global__ __launch_bounds__(512, 2) void gemm320(
    const unsigned short* __restrict__ Ag,
    const unsigned short* __restrict__ Bg,
    unsigned short* __restrict__ C,
    int M, int Cstride)
{
    __shared__ __align__(1024) unsigned short As[3*AB_STR]; // 120 KiB
    __shared__ __align__(1024) unsigned short Bs[2*BB_STR]; //  32 KiB

    // bijective XCD-chunked swizzle (nwg = 256, 256 % 8 == 0)
    const int bid = blockIdx.x;
    const int swz = (bid & 7)*32 + (bid >> 3);
    const int m0 = (swz >> 3) * BMT;   // 32 m-tiles
    const int n0 = (swz & 7) * BNT;    // 8 n-tiles

    const int tid = threadIdx.x;
    const int w   = tid >> 6,  l = tid & 63;
    const int wm  = w >> 1,    wn = w & 1;      // 4(M) x 2(N) wave grid: 80x64/wave
    const int l16 = l & 15,    quad = l >> 4;

    // staging: lane l writes LDS row (g*16 + l>>2), physical chunk (l&3);
    // global source chunk pre-swizzled by row-bit3 = l bit5.
    const int schunk = (l & 3) ^ (((l >> 5) & 1) << 1);
    // reads: logical chunk 'quad' -> physical chunk quad ^ ((row>>3)&1)<<1
    const int rq8   = ((quad ^ (((l16 >> 3) & 1) << 1)) << 3);
    const int a_off = ((wm*80 + l16) << 5) + rq8;
    const int b_off = ((wn*64 + l16) << 5) + rq8;

    // per-wave staging source pointers / LDS dest offsets (static-indexed)
    const unsigned short* asrc[5]; int adst[5];
    #pragma unroll
    for (int p = 0; p < 5; ++p){
        int j = 5*w + p, kh = j/20, g = j - kh*20;
        asrc[p] = Ag + (long)(m0 + g*16 + (l >> 2))*KP + (kh << 5) + (schunk << 3);
        adst[p] = kh*AH_STR + g*512;
    }
    const unsigned short* bsrc[2]; int bdst[2];
    #pragma unroll
    for (int q = 0; q < 2; ++q){
        int j = 2*w + q, kh = j >> 3, g = j & 7;
        bsrc[q] = Bg + (long)(n0 + g*16 + (l >> 2))*KP + (kh << 5) + (schunk << 3);
        bdst[q] = kh*BH_STR + g*512;
    }

    f32x4 acc[5][4];
    #pragma unroll
    for (int i = 0; i < 5; ++i)
        #pragma unroll
        for (int j = 0; j < 4; ++j)
            #pragma unroll
            for (int r = 0; r < 4; ++r) acc[i][j][r] = 0.f;

    // prologue: A(0),B(0)->buf0 [7], A(1),B(1)->buf1 [7]; drain tile-0's 7 only.
    #pragma unroll
    for (int p = 0; p < 5; ++p) STG_A(0, 0, p);
    #pragma unroll
    for (int q = 0; q < 2; ++q) STG_B(0, 0, q);
    #pragma unroll
    for (int p = 0; p < 5; ++p) STG_A(1, AB_STR, p);
    #pragma unroll
    for (int q = 0; q < 2; ++q) STG_B(1, BB_STR, q);
    GATE7;
    BARR;

    int ab = 0, bb = 0;   // buf of tile t: ab = t%3, bb = t&1
    #pragma unroll 1
    for (int t = 0; t < KTILES-2; ++t){
        const int pA  = ab*AB_STR;
        const int pB  = bb*BB_STR;                   // B(t) buf == B(t+2) dest buf
        const int ab2 = (ab == 0) ? 2 : ab - 1;      // (t+2)%3
        const int pA2 = ab2*AB_STR;
        TILE_BODY({ STG_A(t+2,pA2,0); STG_A(t+2,pA2,1); STG_A(t+2,pA2,2); STG_A(t+2,pA2,3); },
                  { STG_A(t+2,pA2,4); STG_B(t+2,pB,0); STG_B(t+2,pB,1); },
                  GATE7)
        ab = (ab == 2) ? 0 : ab + 1;
        bb ^= 1;
    }
    // peeled tile KTILES-2: no staging; full drain (tile-45's loads -> tile-47 data)
    {
        const int pA = ab*AB_STR, pB = bb*BB_STR;
        TILE_BODY(NOOPS, NOOPS, GATE0)
        ab = (ab == 2) ? 0 : ab + 1;
        bb ^= 1;
    }
    // peeled tile KTILES-1: no staging, no gate
    {
        const int pA = ab*AB_STR, pB = bb*BB_STR;
        TILE_BODY(NOOPS, NOOPS, NOOPS)
    }

    // epilogue: C/D layout col=lane&15, row=quad*4+reg
    #pragma unroll
    for (int mt = 0; mt < 5; ++mt){
        const int rowb = m0 + wm*80 + mt*16 + quad*4;
        #pragma unroll
        for (int nt = 0; nt < 4; ++nt){
            const int col = n0 + wn*64 + nt*16 + l16;
            #pragma unroll
            for (int r = 0; r < 4; ++r){
                const int row = rowb + r;
                if (row < M) C[(long)row*Cstride + col] = f2b(acc[mt][nt][r]);
            }
        }
    }
}

// ---------------- 64x64 MFMA GEMM: C = A[ridx?] @ BT^T (+epi) ----------------
// A: MxK bf16, BT: NnxK bf16, K % 32 == 0. epi: 0 none, 1 +bias, 2 +bias+prelu.
// obf: output bf16 (else f32). ridx: optional A row gather.
__device__ __forceinline__ void gemm_bt_body(
    const unsigned short* __restrict__ A,
    const unsigned short* __restrict__ BT,
    void* __restrict__ Cv,
    int M, int Nn, int K, int Cstride,
    const float* __restrict__ bias,
    const float* __restrict__ alpha,
    int epi, const int* __restrict__ ridx, int obf)
{
    __shared__ __align__(16) unsigned short As[64*40];
    __shared__ __align__(16) unsigned short Bs[64*40];
    const int m0 = blockIdx.y*64, n0 = blockIdx.x*64;
    const int t = threadIdx.x;
    const int lrow = t >> 2, lk = (t & 3) * 8;
    const int wave = t >> 6, lane = t & 63;
    const int quad = lane >> 4, l16 = lane & 15;
    f32x4 acc[4];
    #pragma unroll
    for (int i = 0; i < 4; i++)
        for (int j = 0; j < 4; j++) acc[i][j] = 0.f;

    const bool arv = (m0 + lrow) < M;
    const bool brv = (n0 + lrow) < Nn;
    long arow = 0;
    if (arv) arow = ridx ? (long)ridx[m0 + lrow] : (long)(m0 + lrow);
    const long arowbase = arow * K;
    const long browbase = (long)(n0 + lrow) * K;

    for (int k0 = 0; k0 < K; k0 += 32){
        int gk = k0 + lk;
        uint4 av = {0u,0u,0u,0u};
        uint4 bv = {0u,0u,0u,0u};
        if (arv) av = *(const uint4*)(A + arowbase + gk);
        if (brv) bv = *(const uint4*)(BT + browbase + gk);
        *(uint4*)(&As[lrow*40 + lk]) = av;
        *(uint4*)(&Bs[lrow*40 + lk]) = bv;
        __syncthreads();
        bf16x8 af = *(const bf16x8*)(&As[(wave*16 + l16)*40 + quad*8]);
        #pragma unroll
        for (int nt = 0; nt < 4; nt++){
            bf16x8 bfr = *(const bf16x8*)(&Bs[(nt*16 + l16)*40 + quad*8]);
            acc[nt] = __builtin_amdgcn_mfma_f32_16x16x32_bf16(af, bfr, acc[nt], 0, 0, 0);
        }
        __syncthreads();
    }

    const int rowb = m0 + wave*16 + quad*4;
    float aval = (epi == 2) ? alpha[0] : 0.f;
    #pragma unroll
    for (int nt = 0; nt < 4; nt++){
        int col = n0 + nt*16 + l16;
        if (col >= Nn) continue;
        float bvv = epi ? bias[col] : 0.f;
        #pragma unroll
        for (int r = 0; r < 4; r++){
            int row = rowb + r;
            if (row < M){
                float v = acc[nt][r] + bvv;
                if (epi == 2 && v < 0.f) v *= aval;
                if (obf) ((unsigned short*)Cv)[(long)row*Cstride + col] = f2b(v);
                else     ((float*)Cv)[(long)row*Cstride + col] = v;
            }
        }
    }
}

__global__ __launch_bounds__(256) void gemm_bt_ex(
    const unsigned short* __restrict__ A,
    const unsigned short* __restrict__ BT,
    void* __restrict__ Cv,
    int M, int Nn, int K, int Cstride,
    const float* __restrict__ bias,
    const float* __restrict__ alpha,
    int epi, const int* __restrict__ ridx, int obf)
{
    gemm_bt_body(A, BT, Cv, M, Nn, K, Cstride, bias, alpha, epi, ridx, obf);
}

// z-batched pair variant: blockIdx.z selects the (A,B,C,bias,alpha) set.
__global__ __launch_bounds__(256) void gemm_bt2(
    const unsigned short* __restrict__ A0, const unsigned short* __restrict__ A1,
    const unsigned short* __restrict__ B0, const unsigned short* __restrict__ B1,
    void* __restrict__ C0, void* __restrict__ C1,
    int M, int Nn, int K, int Cstride,
    const float* __restrict__ bias0, const float* __restrict__ bias1,
    const float* __restrict__ al0, const float* __restrict__ al1,
    int epi, const int* __restrict__ ridx, int obf)
{
    if (blockIdx.z == 0)
        gemm_bt_body(A0, B0, C0, M, Nn, K, Cstride, bias0, al0, epi, ridx, obf);
    else
        gemm_bt_body(A1, B1, C1, M, Nn, K, Cstride, bias1, al1, epi, ridx, obf);
}

// ---------------- fused GCN layer-1 aggregation (pos + neg), bf16 I/O ----------------

__global__ __launch_bounds__(256) void agg1_k(const unsigned short* __restrict__ XW,
    const float* __restrict__ ptW, const float* __restrict__ ntW,
    const int* __restrict__ flag, const int* __restrict__ negsrc,
    const float* __restrict__ dinv, const int* __restrict__ rowptr,
    const int* __restrict__ degi, const int* __restrict__ adj,
    const float* __restrict__ sb1, const float* __restrict__ sav,
    const float* __restrict__ tb1, const float* __restrict__ tav,
    unsigned short* __restrict__ H1p, unsigned short* __restrict__ H1n)
{
    int i = blockIdx.x; int t = threadIdx.x;
    int c = 2*t;                       // cols c, c+1 in [0,512)
    float di = dinv[i];
    int rs = rowptr[i], re = rs + degi[i];
    float p0 = ptW[c], p1 = ptW[c+1];
    float n0v = ntW[c], n1v = ntW[c+1];
    int fi = flag[i];
    int nsi = negsrc[i]; if (nsi < 0) nsi = 0;
    float ffi = fi ? 1.f : 0.f;
    float2 xp = bpair(*(const unsigned int*)(XW + (long)i*1024 + c));
    float2 xn = bpair(*(const unsigned int*)(XW + (long)nsi*1024 + 512 + c));
    float pa0 = (xp.x + ffi*p0) * di;
    float pa1 = (xp.y + ffi*p1) * di;
    float na0 = (fi ? n0v : xn.x) * di;
    float na1 = (fi ? n1v : xn.y) * di;
    for (int e = rs; e < re; ++e){
        int s = adj[e]; float ds = dinv[s];
        int fs = flag[s];
        int ns = negsrc[s]; if (ns < 0) ns = 0;
        float ffs = fs ? 1.f : 0.f;
        float2 sp = bpair(*(const unsigned int*)(XW + (long)s*1024 + c));
        float2 sn = bpair(*(const unsigned int*)(XW + (long)ns*1024 + 512 + c));
        pa0 += (sp.x + ffs*p0) * ds;
        pa1 += (sp.y + ffs*p1) * ds;
        na0 += (fs ? n0v : sn.x) * ds;
        na1 += (fs ? n1v : sn.y) * ds;
    }
    float sa_ = sav[0], ta_ = tav[0];
    float v0 = di*pa0 + sb1[c];   if (v0 < 0.f) v0 *= sa_;
    float v1 = di*pa1 + sb1[c+1]; if (v1 < 0.f) v1 *= sa_;
    float w0 = di*na0 + tb1[c];   if (w0 < 0.f) w0 *= ta_;
    float w1 = di*na1 + tb1[c+1]; if (w1 < 0.f) w1 *= ta_;
    *(unsigned int*)(H1p + (long)i*512 + c) = packb(v0, v1);
    *(unsigned int*)(H1n + (long)i*512 + c) = packb(w0, w1);
}

__global__ __launch_bounds__(128) void agg128_k(const unsigned short* __restrict__ In,
    const float* __restrict__ dinv, const int* __restrict__ rowptr,
    const int* __restrict__ degi, const int* __restrict__ adj,
    const float* __restrict__ b2, const float* __restrict__ a2,
    unsigned short* __restrict__ Out)
{
    int i = blockIdx.x, t = threadIdx.x;
    float di = dinv[i];
    int rs = rowptr[i], re = rs + degi[i];
    float acc = b2f(In[(long)i*128 + t]) * di;
    for (int e = rs; e < re; ++e){
        int s = adj[e];
        acc += b2f(In[(long)s*128 + t]) * dinv[s];
    }
    float v = di*acc + b2[t];
    float a = a2[0]; if (v < 0.f) v *= a;
    Out[(long)i*128 + t] = f2b(v);
}

__global__ __launch_bounds__(128) void aggrec_k(const unsigned short* __restrict__ recPre,
    const float* __restrict__ dinv, const int* __restrict__ rowptr,
    const int* __restrict__ degi, const int* __restrict__ adj,
    const int* __restrict__ flag, const int* __restrict__ perm,
    unsigned short* __restrict__ recAgg)
{
    int b = blockIdx.x, t = threadIdx.x;
    int i = perm[b];
    float di = dinv[i];
    int rs = rowptr[i], re = rs + degi[i];
    float acc = 0.f; // self loop: i is a mask node -> rec row zeroed
    for (int e = rs; e < re; ++e){
        int s = adj[e];
        if (!flag[s]) acc += b2f(recPre[(long)s*128 + t]) * dinv[s];
    }
    recAgg[(long)b*128 + t] = f2b(di * acc);
}

// ---------------- DGI head ----------------

__global__ __launch_bounds__(128) void meanp_k(const float* __restrict__ posZ,
                                               float* svecraw){
    int j = threadIdx.x;
    int r0 = blockIdx.x*64, r1 = r0 + 64; if (r1 > NM) r1 = NM;
    float s = 0.f;
    for (int r = r0; r < r1; ++r) s += posZ[(long)r*128 + j];
    atomicAdd(&svecraw[j], s);
}

__global__ void ws_k(const float* __restrict__ dgiW, const float* __restrict__ svecraw,
                     float* wsv){
    __shared__ float s[128];
    int i = threadIdx.x; // 128
    s[i] = 1.f/(1.f + expf(-svecraw[i]/(float)NM));
    __syncthreads();
    float a = 0.f;
    for (int j = 0; j < 128; ++j) a += dgiW[i*128 + j] * s[j];
    wsv[i] = a;
}

__global__ __launch_bounds__(256) void dgi_k(const float* __restrict__ posZ,
    const float* __restrict__ negZ, const float* __restrict__ wsv, float* scal){
    int row = blockIdx.x*4 + (threadIdx.x >> 6);
    int lane = threadIdx.x & 63;
    if (row >= 2*NM) return;
    const float* Z = (row < NM) ? posZ : negZ;
    int r = (row < NM) ? row : row - NM;
    float v = Z[(long)r*128 + lane] * wsv[lane]
            + Z[(long)r*128 + 64 + lane] * wsv[64 + lane];
    for (int off = 32; off; off >>= 1) v += __shfl_down(v, off, 64);
    if (lane == 0){
        float d = 1.f/(1.f + expf(-v));
        float lg = (row < NM) ? logf(d + 1e-15f) : logf(1.f - d + 1e-15f);
        atomicAdd(&scal[(row < NM) ? 0 : 1], lg);
    }
}

// ---------------- cosine feature loss ----------------

__global__ __launch_bounds__(256) void cos_k(const float* __restrict__ x,
    const unsigned short* __restrict__ recMask, const int* __restrict__ perm,
    float* scal){
    int b = blockIdx.x, t = threadIdx.x;
    long xi = (long)perm[b]*DD;
    long ri = (long)b*DD;
    float dot = 0.f, nx = 0.f, nr = 0.f;
    for (int d = t; d < DD; d += 256){
        float xv = x[xi + d], rv = b2f(recMask[ri + d]);
        dot += xv*rv; nx += xv*xv; nr += rv*rv;
    }
    for (int off = 32; off; off >>= 1){
        dot += __shfl_down(dot, off, 64);
        nx  += __shfl_down(nx,  off, 64);
        nr  += __shfl_down(nr,  off, 64);
    }
    __shared__ float sd[4], sx[4], sr[4];
    int w = t >> 6, lane = t & 63;
    if (lane == 0){ sd[w] = dot; sx[w] = nx; sr[w] = nr; }
    __syncthreads();
    if (t == 0){
        float Dv = sd[0]+sd[1]+sd[2]+sd[3];
        float Xv = sx[0]+sx[1]+sx[2]+sx[3];
        float Rv = sr[0]+sr[1]+sr[2]+sr[3];
        float c = Dv/(fmaxf(sqrtf(Xv),1e-12f)*fmaxf(sqrtf(Rv),1e-12f));
        float e = 1.f - c;
        atomicAdd(&scal[2], e*e);
    }
}

__global__ void fin_k(const float* __restrict__ scal, float* out){
    float feat = scal[2]/(float)NM;
    float dgi  = -(scal[0]/(float)NM) - (scal[1]/(float)NM);
    out[0] = feat;
    out[1] = dgi;
}

// ---------------- launch ----------------

extern "C" void kernel_launch(void* const* d_in, const int* in_sizes, int n_in,
                              void* d_out, int out_size, void* d_ws, size_t ws_size,
                              hipStream_t stream) {
    (void)in_sizes; (void)n_in; (void)out_size; (void)d_ws; (void)ws_size;
    const float* x  = (const float*)d_in[0];
    const int* ei   = (const int*)d_in[1];
    const int* perm = (const int*)d_in[2];
    const int* shuf = (const int*)d_in[3];
    const float* sW1 = (const float*)d_in[4];
    const float* sb1 = (const float*)d_in[5];
    const float* sa  = (const float*)d_in[6];
    const float* sW2 = (const float*)d_in[7];
    const float* sb2 = (const float*)d_in[8];
    const float* tW1 = (const float*)d_in[9];
    const float* tb1 = (const float*)d_in[10];
    const float* ta  = (const float*)d_in[11];
    const float* tW2 = (const float*)d_in[12];
    const float* tb2 = (const float*)d_in[13];
    const float* pW1 = (const float*)d_in[14];
    const float* pb1 = (const float*)d_in[15];
    const float* pa  = (const float*)d_in[16];
    const float* pW2 = (const float*)d_in[17];
    const float* pb2 = (const float*)d_in[18];
    const float* tpW1 = (const float*)d_in[19];
    const float* tpb1 = (const float*)d_in[20];
    const float* tpa  = (const float*)d_in[21];
    const float* tpW2 = (const float*)d_in[22];
    const float* tpb2 = (const float*)d_in[23];
    const float* dgiW = (const float*)d_in[24];
    const float* posT = (const float*)d_in[25];
    const float* negT = (const float*)d_in[26];
    const float* e2dW = (const float*)d_in[27];
    const float* dW   = (const float*)d_in[28];
    const float* db   = (const float*)d_in[29];
    float* out = (float*)d_out;

    void* wsp = nullptr;
    hipGetSymbolAddress(&wsp, HIP_SYMBOL(g_ws));
    char* base = (char*)wsp;
    size_t off = 0;
    auto alloc = [&](size_t b){ size_t o = off; off = (off + b + 255) & ~(size_t)255; return o; };

    float* dinv    = (float*)(base + alloc(NND*4));
    int* degi      = (int*)  (base + alloc(NND*4));
    int* rowptr    = (int*)  (base + alloc(NND*4));
    int* cursor    = (int*)  (base + alloc(NND*4));
    int* adj       = (int*)  (base + alloc(EE*4));
    int* flag      = (int*)  (base + alloc(NND*4));
    int* negsrc    = (int*)  (base + alloc(NND*4));
    int* ecnt      = (int*)  (base + alloc(16*4));
    float* ptW     = (float*)(base + alloc(HH*4));
    float* ntW     = (float*)(base + alloc(HH*4));
    float* svecraw = (float*)(base + alloc(128*4));
    float* wsv     = (float*)(base + alloc(128*4));
    float* scal    = (float*)(base + alloc(16*4));

    unsigned short* xb    = (unsigned short*)(base + alloc((size_t)MP*KP*2));
    unsigned short* W1T   = (unsigned short*)(base + alloc((size_t)NW*KP*2));
    unsigned short* sW2T  = (unsigned short*)(base + alloc((size_t)LL*HH*2));
    unsigned short* tW2T  = (unsigned short*)(base + alloc((size_t)LL*HH*2));
    unsigned short* pW1T  = (unsigned short*)(base + alloc((size_t)PP*LL*2));
    unsigned short* pW2T  = (unsigned short*)(base + alloc((size_t)LL*PP*2));
    unsigned short* tpW1T = (unsigned short*)(base + alloc((size_t)PP*LL*2));
    unsigned short* tpW2T = (unsigned short*)(base + alloc((size_t)LL*PP*2));
    unsigned short* e2dWT = (unsigned short*)(base + alloc((size_t)LL*LL*2));
    unsigned short* dWT   = (unsigned short*)(base + alloc((size_t)DD*LL*2));

    unsigned short* XW      = (unsigned short*)(base + alloc((size_t)NND*1024*2));
    unsigned short* H1p     = (unsigned short*)(base + alloc((size_t)NND*512*2));
    unsigned short* H1n     = (unsigned short*)(base + alloc((size_t)NND*512*2));
    unsigned short* M2p     = (unsigned short*)(base + alloc((size_t)NND*128*2));
    unsigned short* M2n     = (unsigned short*)(base + alloc((size_t)NND*128*2));
    unsigned short* repP    = (unsigned short*)(base + alloc((size_t)NND*128*2));
    unsigned short* repN    = (unsigned short*)(base + alloc((size_t)NND*128*2));
    unsigned short* posH    = (unsigned short*)(base + alloc((size_t)NM*256*2));
    unsigned short* negH    = (unsigned short*)(base + alloc((size_t)NM*256*2));
    float* posZ             = (float*)(base + alloc((size_t)NM*128*4));
    float* negZ             = (float*)(base + alloc((size_t)NM*128*4));
    unsigned short* recPre  = (unsigned short*)(base + alloc((size_t)NND*128*2));
    unsigned short* recAgg  = (unsigned short*)(base + alloc((size_t)NM*128*2));
    unsigned short* recMask = (unsigned short*)(base + alloc((size_t)NM*DD*2));

    // ---- graph build (scan-free) ----
    init_k<<<(NND+255)/256, 256, 0, stream>>>(degi, cursor, scal, ptW, ntW, svecraw, ecnt);
    flag_k<<<(NND+255)/256, 256, 0, stream>>>(perm, shuf, flag, negsrc);
    count_k<<<(EE+255)/256, 256, 0, stream>>>(ei, degi);
    alloc_k<<<(NND+255)/256, 256, 0, stream>>>(degi, dinv, rowptr, ecnt);
    fill_k<<<(EE+255)/256, 256, 0, stream>>>(ei, rowptr, cursor, adj);
    tok_k<<<dim3(2,8), 512, 0, stream>>>(posT, negT, sW1, tW1, ptW, ntW);

    // ---- bf16 staging ----
    cast_pad_x_k<<<(int)(((long)MP*(KP/8) + 255)/256), 256, 0, stream>>>(x, xb);
    {
        TBatch tb;
        const float* ins[10] = {sW1, tW1, sW2, tW2, pW1, pW2, tpW1, tpW2, e2dW, dW};
        unsigned short* outs[10] = {W1T, W1T + (size_t)HH*KP, sW2T, tW2T, pW1T, pW2T,
                                    tpW1T, tpW2T, e2dWT, dWT};
        int Rs[10]  = {DD, DD, HH, HH, LL, PP, LL, PP, LL, LL};
        int Cs[10]  = {HH, HH, LL, LL, PP, LL, PP, LL, LL, DD};
        int OSs[10] = {KP, KP, HH, HH, LL, PP, LL, PP, LL, LL};
        int cum = 0;
        for (int d = 0; d < 10; d++){
            tb.in[d] = ins[d]; tb.out[d] = outs[d];
            tb.R[d] = Rs[d]; tb.C[d] = Cs[d]; tb.OS[d] = OSs[d];
            tb.t0[d] = cum;
            cum += (OSs[d]/32) * ((Cs[d] + 31)/32);
        }
        tb.t0[10] = cum;
        transbatch_k<<<cum, dim3(32,8), 0, stream>>>(tb);
    }

    // ---- encoder layer 1 (MFMA 320x128, 256 blocks) + fused aggregation ----
    gemm320<<<256, 512, 0, stream>>>(xb, W1T, XW, NND, 1024);
    agg1_k<<<NND, 256, 0, stream>>>(XW, ptW, ntW, flag, negsrc, dinv, rowptr, degi, adj,
                                    sb1, sa, tb1, ta, H1p, H1n);

    // ---- encoder layer 2 (MFMA, z-batched pair) ----
    gemm_bt2<<<dim3(2,157,2), 256, 0, stream>>>(H1p, H1n, sW2T, tW2T, M2p, M2n,
                                                NND, LL, HH, LL,
                                                nullptr, nullptr, nullptr, nullptr,
                                                0, nullptr, 1);
    agg128_k<<<NND, 128, 0, stream>>>(M2p, dinv, rowptr, degi, adj, sb2, sa, repP);
    agg128_k<<<NND, 128, 0, stream>>>(M2n, dinv, rowptr, degi, adj, tb2, ta, repN);

    // ---- projections on mask rows (MFMA, gathered A via perm, z-batched) ----
    gemm_bt2<<<dim3(4,47,2), 256, 0, stream>>>(repP, repN, pW1T, tpW1T, posH, negH,
                                               NM, PP, LL, PP,
                                               pb1, tpb1, pa, tpa, 2, perm, 1);
    gemm_bt2<<<dim3(2,47,2), 256, 0, stream>>>(posH, negH, pW2T, tpW2T, posZ, negZ,
                                               NM, LL, PP, LL,
                                               pb2, tpb2, nullptr, nullptr, 1, nullptr, 0);

    // ---- DGI loss ----
    meanp_k<<<47, 128, 0, stream>>>(posZ, svecraw);
    ws_k<<<1, 128, 0, stream>>>(dgiW, svecraw, wsv);
    dgi_k<<<(2*NM)/4, 256, 0, stream>>>(posZ, negZ, wsv, scal);

    // ---- decoder + feature loss (MFMA) ----
    gemm_bt_ex<<<dim3(2,157), 256, 0, stream>>>(repP, e2dWT, recPre, NND, LL, LL, LL,
                                                nullptr, nullptr, 0, nullptr, 1);
    aggrec_k<<<NM, 128, 0, stream>>>(recPre, dinv, rowptr, degi, adj, flag, perm, recAgg);
    gemm_bt_ex<<<dim3(47,47), 256, 0, stream>>>(recAgg, dWT, recMask, NM, DD, LL, DD,
                                                db, nullptr, 1, nullptr, 1);
    cos_k<<<NM, 256, 0, stream>>>(x, recMask, perm, scal);

    fin_k<<<1, 1, 0, stream>>>(scal, out);
}

// Round 4
// 524.006 us; speedup vs baseline: 1.3064x; 1.1708x over previous
//
#include <hip/hip_runtime.h>

#define NND 10000
#define EE  60000
#define DD  3000
#define HH  512
#define LL  128
#define PP  256
#define NM  3000

// padded dims for the big MFMA GEMM (no tail guards in hot loop)
#define KP  3072            // 48 * 64
#define MP  10240           // 32 * 320
#define NW  1024            // [sW1|tW1] fused width, 8*128
#define KTILES (KP/64)      // 48

// gemm320 tile geometry
#define BMT 320
#define BNT 128
#define AH_STR 10240        // elems per A k-half (320 rows x 32)
#define AB_STR 20480        // elems per A buf (2 k-halves)
#define BH_STR 4096         // elems per B k-half (128 rows x 32)
#define BB_STR 8192         // elems per B buf

typedef short bf16x8 __attribute__((ext_vector_type(8)));
typedef float f32x4 __attribute__((ext_vector_type(4)));

// All scratch lives in module BSS -> no dependency on harness ws_size.
__device__ __align__(256) char g_ws[(size_t)176 << 20];

__device__ __forceinline__ unsigned short f2b(float f){
    unsigned int x = __float_as_uint(f);
    unsigned int r = x + 0x7FFFu + ((x >> 16) & 1u);
    return (unsigned short)(r >> 16);
}
__device__ __forceinline__ float b2f(unsigned short u){
    return __uint_as_float(((unsigned int)u) << 16);
}
// uint holding 2 bf16 (low = col c, high = col c+1)
__device__ __forceinline__ float2 bpair(unsigned int u){
    float2 r;
    r.x = __uint_as_float(u << 16);
    r.y = __uint_as_float(u & 0xffff0000u);
    return r;
}
__device__ __forceinline__ unsigned int packb(float a, float b){
    return (unsigned int)f2b(a) | ((unsigned int)f2b(b) << 16);
}

__device__ __forceinline__ void gl_lds16(const void* g, void* l){
    __builtin_amdgcn_global_load_lds(
        (const __attribute__((address_space(1))) unsigned int*)g,
        (__attribute__((address_space(3))) unsigned int*)l, 16, 0, 0);
}

// ---------------- init / graph build ----------------

__global__ void init_k(int* degi, int* cursor, float* scal,
                       float* ptW, float* ntW, float* svecraw, int* ecnt){
    int i = blockIdx.x*256 + threadIdx.x;
    if (i < NND){ degi[i]=0; cursor[i]=0; }
    if (i < 80) scal[i]=0.f;           // [0]=dgi-pos [1]=dgi-neg [16..79]=cos slots
    if (i == 0) ecnt[0]=0;
    if (i < 128) svecraw[i]=0.f;
    if (i < HH){ ptW[i]=0.f; ntW[i]=0.f; }
}

__global__ void count_k(const int* __restrict__ ei, int* degi){
    int i = blockIdx.x*256 + threadIdx.x;
    if (i < EE) atomicAdd(&degi[ei[EE + i]], 1);
}

__global__ void flag_k(const int* __restrict__ perm, const int* __restrict__ shuf,
                       int* flag, int* negsrc){
    int i = blockIdx.x*256 + threadIdx.x;
    if (i < NND){
        int p = perm[i];
        if (i < NM){ flag[p] = 1; negsrc[p] = -1; }
        else       { flag[p] = 0; negsrc[p] = perm[NM + shuf[i - NM]]; }
    }
}

// dinv + CSR segment allocation (order-free; per-block scan, 1 atomic/block)
__global__ __launch_bounds__(256) void alloc_k(const int* __restrict__ degi,
                                               float* dinv, int* rowptr, int* ecnt){
    __shared__ int sb[256];
    __shared__ int bbase;
    int t = threadIdx.x;
    int i = blockIdx.x*256 + t;
    int v = (i < NND) ? degi[i] : 0;
    sb[t] = v;
    __syncthreads();
    for (int off = 1; off < 256; off <<= 1){
        int x = 0;
        if (t >= off) x = sb[t - off];
        __syncthreads();
        sb[t] += x;
        __syncthreads();
    }
    if (t == 255) bbase = atomicAdd(ecnt, sb[255]);
    __syncthreads();
    if (i < NND){
        rowptr[i] = bbase + sb[t] - v;
        dinv[i] = 1.f/sqrtf((float)(degi[i] + 1));
    }
}

__global__ void fill_k(const int* __restrict__ ei, const int* __restrict__ rowptr,
                       int* cursor, int* adj){
    int i = blockIdx.x*256 + threadIdx.x;
    if (i < EE){
        int d = ei[EE + i];
        int s = ei[i];
        int p = atomicAdd(&cursor[d], 1);
        adj[rowptr[d] + p] = s;
    }
}

// token @ W1 partial sums
__global__ __launch_bounds__(512) void tok_k(const float* __restrict__ posT,
        const float* __restrict__ negT,
        const float* __restrict__ sW1, const float* __restrict__ tW1,
        float* ptW, float* ntW){
    int b = blockIdx.x; int chunk = blockIdx.y; int j = threadIdx.x;
    const float* tok = b ? negT : posT;
    const float* Wm  = b ? tW1  : sW1;
    float acc = 0.f;
    int d0 = chunk * (DD/8), d1 = d0 + (DD/8);
    for (int d = d0; d < d1; ++d) acc += tok[d] * Wm[(long)d*HH + j];
    atomicAdd(&((b ? ntW : ptW)[j]), acc);
}

// ---------------- casts for MFMA path ----------------

__global__ __launch_bounds__(256) void cast_pad_x_k(const float* __restrict__ x,
                                                    unsigned short* __restrict__ xb){
    long idx = (long)blockIdx.x*256 + threadIdx.x;
    if (idx >= (long)MP*(KP/8)) return;
    int row = (int)(idx / (KP/8));
    int g   = (int)(idx % (KP/8));
    unsigned short o[8] = {0,0,0,0,0,0,0,0};
    if (row < NND && g < DD/8){
        const float* src = x + (long)row*DD + g*8;
        float4 a = *(const float4*)(src);
        float4 b = *(const float4*)(src + 4);
        o[0]=f2b(a.x); o[1]=f2b(a.y); o[2]=f2b(a.z); o[3]=f2b(a.w);
        o[4]=f2b(b.x); o[5]=f2b(b.y); o[6]=f2b(b.z); o[7]=f2b(b.w);
    }
    *(uint4*)(xb + (long)row*KP + g*8) = *(const uint4*)o;
}

// batched transpose-cast: out[c*OS + r] = bf16(in[r*C + c]), zero-fill r in [R,OS)
struct TBatch {
    const float* in[10];
    unsigned short* out[10];
    int R[10], C[10], OS[10];
    int t0[11];
};

__global__ void transbatch_k(TBatch tb){
    __shared__ unsigned short tile[32][33];
    int b = blockIdx.x;
    int d = 0;
    while (d < 9 && b >= tb.t0[d+1]) d++;
    const float* in = tb.in[d];
    unsigned short* out = tb.out[d];
    int R = tb.R[d], C = tb.C[d], OS = tb.OS[d];
    int lt = b - tb.t0[d];
    int Ctiles = (C + 31) >> 5;
    int rt = lt / Ctiles, ct = lt % Ctiles;
    int rb = rt*32, cb = ct*32;
    int tx = threadIdx.x, ty = threadIdx.y; // (32,8)
    for (int i = ty; i < 32; i += 8){
        int r = rb + i, c = cb + tx;
        tile[i][tx] = (r < R && c < C) ? f2b(in[(long)r*C + c]) : (unsigned short)0;
    }
    __syncthreads();
    for (int i = ty; i < 32; i += 8){
        int c = cb + i, r = rb + tx;
        if (c < C && r < OS) out[(long)c*OS + r] = (r < R) ? tile[tx][i] : (unsigned short)0;
    }
}

// ---------------- 320x128 MFMA GEMM, 256 blocks (1/CU), 3-barrier tiles --------
// A: MP x KP bf16, Bg: NW x KP bf16 (row = output col). C guarded to M rows.
// A triple-buffered (3 x 40 KiB), B double-buffered (2 x 16 KiB) = 152 KiB LDS.
// Per K-tile: [18 frag ds_reads + 4 A-prefetch gl_lds] BAR [16 MFMA mt0-1] BAR
//             [1 A + 2 B gl_lds] [24 MFMA mt2-4] vmcnt(7) BAR.
// Reads are issued BEFORE the rendezvous so the barrier absorbs LDS latency;
// compiler inserts counted lgkmcnt before each dependent MFMA (no asm wall).
// Hazards: A(t+2) buf is distinct from A(t),A(t+1) (triple buffer) -> safe at
// phase 1. B(t+2) overwrites B(t)'s buffer -> issued only after BAR2 (all
// waves' B reads complete). Gate vmcnt(7) + BAR3 drains tile t-1's 7 loads
// before tile t+1 reads them (per-wave vmcnt + rendezvous = global drain).
// Swizzle (both-sides, rule 21): linear LDS dest; global source chunk pre-XOR'd
// with ((row>>3)&1)<<1; reads XOR the same involution. Zero bank conflicts (meas.).

#define LDA(PB, MT, KS) (*(const bf16x8*)&As[(PB) + (KS)*AH_STR + a_off + (MT)*512])
#define LDB(PB, NT, KS) (*(const bf16x8*)&Bs[(PB) + (KS)*BH_STR + b_off + (NT)*512])

#define STG_A(KT, PDST, P) gl_lds16(asrc[P] + ((KT)<<6), &As[(PDST) + adst[P]])
#define STG_B(KT, PDST, Q) gl_lds16(bsrc[Q] + ((KT)<<6), &Bs[(PDST) + bdst[Q]])

#define GATE7 asm volatile("s_waitcnt vmcnt(7)" ::: "memory")
#define GATE0 asm volatile("s_waitcnt vmcnt(0)" ::: "memory")
#define NOOPS ((void)0)
#define AFENCE asm volatile("" ::: "memory")
#define BARR  { AFENCE; __builtin_amdgcn_s_barrier(); AFENCE; }

#define TILE_BODY(S1_STMT, S2_STMT, GATE_STMT) {                                  \
    bf16x8 af_[5][2], bf_[4][2];                                                  \
    _Pragma("unroll") for (int nt = 0; nt < 4; ++nt){                             \
        bf_[nt][0] = LDB(pB, nt, 0); bf_[nt][1] = LDB(pB, nt, 1); }               \
    _Pragma("unroll") for (int mt = 0; mt < 5; ++mt){                             \
        af_[mt][0] = LDA(pA, mt, 0); af_[mt][1] = LDA(pA, mt, 1); }               \
    S1_STMT;                                                                      \
    BARR;                                                                         \
    __builtin_amdgcn_s_setprio(1);                                                \
    _Pragma("unroll") for (int ks = 0; ks < 2; ++ks)                              \
      _Pragma("unroll") for (int nt = 0; nt < 4; ++nt)                            \
        _Pragma("unroll") for (int mt = 0; mt < 2; ++mt)                          \
          acc[mt][nt] = __builtin_amdgcn_mfma_f32_16x16x32_bf16(af_[mt][ks], bf_[nt][ks], acc[mt][nt], 0,0,0); \
    __builtin_amdgcn_s_setprio(0);                                                \
    BARR;                                                                         \
    S2_STMT;                                                                      \
    __builtin_amdgcn_s_setprio(1);                                                \
    _Pragma("unroll") for (int ks = 0; ks < 2; ++ks)                              \
      _Pragma("unroll") for (int nt = 0; nt < 4; ++nt)                            \
        _Pragma("unroll") for (int mt = 2; mt < 5; ++mt)                          \
          acc[mt][nt] = __builtin_amdgcn_mfma_f32_16x16x32_bf16(af_[mt][ks], bf_[nt][ks], acc[mt][nt], 0,0,0); \
    __builtin_amdgcn_s_setprio(0);                                                \
    GATE_STMT;                                                                    \
    BARR;                                                                         \
}

__global__ __launch_bounds__(512, 2) void gemm320(
    const unsigned short* __restrict__ Ag,
    const unsigned short* __restrict__ Bg,
    unsigned short* __restrict__ C,
    int M, int Cstride)
{
    __shared__ __align__(1024) unsigned short As[3*AB_STR]; // 120 KiB
    __shared__ __align__(1024) unsigned short Bs[2*BB_STR]; //  32 KiB

    // bijective XCD-chunked swizzle (nwg = 256, 256 % 8 == 0)
    const int bid = blockIdx.x;
    const int swz = (bid & 7)*32 + (bid >> 3);
    const int m0 = (swz >> 3) * BMT;   // 32 m-tiles
    const int n0 = (swz & 7) * BNT;    // 8 n-tiles

    const int tid = threadIdx.x;
    const int w   = tid >> 6,  l = tid & 63;
    const int wm  = w >> 1,    wn = w & 1;      // 4(M) x 2(N) wave grid: 80x64/wave
    const int l16 = l & 15,    quad = l >> 4;

    // staging: lane l writes LDS row (g*16 + l>>2), physical chunk (l&3);
    // global source chunk pre-swizzled by row-bit3 = l bit5.
    const int schunk = (l & 3) ^ (((l >> 5) & 1) << 1);
    // reads: logical chunk 'quad' -> physical chunk quad ^ ((row>>3)&1)<<1
    const int rq8   = ((quad ^ (((l16 >> 3) & 1) << 1)) << 3);
    const int a_off = ((wm*80 + l16) << 5) + rq8;
    const int b_off = ((wn*64 + l16) << 5) + rq8;

    // per-wave staging source pointers / LDS dest offsets (static-indexed)
    const unsigned short* asrc[5]; int adst[5];
    #pragma unroll
    for (int p = 0; p < 5; ++p){
        int j = 5*w + p, kh = j/20, g = j - kh*20;
        asrc[p] = Ag + (long)(m0 + g*16 + (l >> 2))*KP + (kh << 5) + (schunk << 3);
        adst[p] = kh*AH_STR + g*512;
    }
    const unsigned short* bsrc[2]; int bdst[2];
    #pragma unroll
    for (int q = 0; q < 2; ++q){
        int j = 2*w + q, kh = j >> 3, g = j & 7;
        bsrc[q] = Bg + (long)(n0 + g*16 + (l >> 2))*KP + (kh << 5) + (schunk << 3);
        bdst[q] = kh*BH_STR + g*512;
    }

    f32x4 acc[5][4];
    #pragma unroll
    for (int i = 0; i < 5; ++i)
        #pragma unroll
        for (int j = 0; j < 4; ++j)
            #pragma unroll
            for (int r = 0; r < 4; ++r) acc[i][j][r] = 0.f;

    // prologue: A(0),B(0)->buf0 [7], A(1),B(1)->buf1 [7]; drain tile-0's 7 only.
    #pragma unroll
    for (int p = 0; p < 5; ++p) STG_A(0, 0, p);
    #pragma unroll
    for (int q = 0; q < 2; ++q) STG_B(0, 0, q);
    #pragma unroll
    for (int p = 0; p < 5; ++p) STG_A(1, AB_STR, p);
    #pragma unroll
    for (int q = 0; q < 2; ++q) STG_B(1, BB_STR, q);
    GATE7;
    BARR;

    int ab = 0, bb = 0;   // buf of tile t: ab = t%3, bb = t&1
    #pragma unroll 1
    for (int t = 0; t < KTILES-2; ++t){
        const int pA  = ab*AB_STR;
        const int pB  = bb*BB_STR;                   // B(t) buf == B(t+2) dest buf
        const int ab2 = (ab == 0) ? 2 : ab - 1;      // (t+2)%3
        const int pA2 = ab2*AB_STR;
        TILE_BODY({ STG_A(t+2,pA2,0); STG_A(t+2,pA2,1); STG_A(t+2,pA2,2); STG_A(t+2,pA2,3); },
                  { STG_A(t+2,pA2,4); STG_B(t+2,pB,0); STG_B(t+2,pB,1); },
                  GATE7)
        ab = (ab == 2) ? 0 : ab + 1;
        bb ^= 1;
    }
    // peeled tile KTILES-2: no staging; full drain (tile-45's loads -> tile-47 data)
    {
        const int pA = ab*AB_STR, pB = bb*BB_STR;
        TILE_BODY(NOOPS, NOOPS, GATE0)
        ab = (ab == 2) ? 0 : ab + 1;
        bb ^= 1;
    }
    // peeled tile KTILES-1: no staging, no gate
    {
        const int pA = ab*AB_STR, pB = bb*BB_STR;
        TILE_BODY(NOOPS, NOOPS, NOOPS)
    }

    // epilogue: C/D layout col=lane&15, row=quad*4+reg
    #pragma unroll
    for (int mt = 0; mt < 5; ++mt){
        const int rowb = m0 + wm*80 + mt*16 + quad*4;
        #pragma unroll
        for (int nt = 0; nt < 4; ++nt){
            const int col = n0 + wn*64 + nt*16 + l16;
            #pragma unroll
            for (int r = 0; r < 4; ++r){
                const int row = rowb + r;
                if (row < M) C[(long)row*Cstride + col] = f2b(acc[mt][nt][r]);
            }
        }
    }
}

// ---------------- 64x64 MFMA GEMM: C = A[ridx?] @ BT^T (+epi) ----------------
// A: MxK bf16, BT: NnxK bf16, K % 32 == 0. epi: 0 none, 1 +bias, 2 +bias+prelu.
// obf: output bf16 (else f32). ridx: optional A row gather.
__device__ __forceinline__ void gemm_bt_body(
    const unsigned short* __restrict__ A,
    const unsigned short* __restrict__ BT,
    void* __restrict__ Cv,
    int M, int Nn, int K, int Cstride,
    const float* __restrict__ bias,
    const float* __restrict__ alpha,
    int epi, const int* __restrict__ ridx, int obf)
{
    __shared__ __align__(16) unsigned short As[64*40];
    __shared__ __align__(16) unsigned short Bs[64*40];
    const int m0 = blockIdx.y*64, n0 = blockIdx.x*64;
    const int t = threadIdx.x;
    const int lrow = t >> 2, lk = (t & 3) * 8;
    const int wave = t >> 6, lane = t & 63;
    const int quad = lane >> 4, l16 = lane & 15;
    f32x4 acc[4];
    #pragma unroll
    for (int i = 0; i < 4; i++)
        for (int j = 0; j < 4; j++) acc[i][j] = 0.f;

    const bool arv = (m0 + lrow) < M;
    const bool brv = (n0 + lrow) < Nn;
    long arow = 0;
    if (arv) arow = ridx ? (long)ridx[m0 + lrow] : (long)(m0 + lrow);
    const long arowbase = arow * K;
    const long browbase = (long)(n0 + lrow) * K;

    for (int k0 = 0; k0 < K; k0 += 32){
        int gk = k0 + lk;
        uint4 av = {0u,0u,0u,0u};
        uint4 bv = {0u,0u,0u,0u};
        if (arv) av = *(const uint4*)(A + arowbase + gk);
        if (brv) bv = *(const uint4*)(BT + browbase + gk);
        *(uint4*)(&As[lrow*40 + lk]) = av;
        *(uint4*)(&Bs[lrow*40 + lk]) = bv;
        __syncthreads();
        bf16x8 af = *(const bf16x8*)(&As[(wave*16 + l16)*40 + quad*8]);
        #pragma unroll
        for (int nt = 0; nt < 4; nt++){
            bf16x8 bfr = *(const bf16x8*)(&Bs[(nt*16 + l16)*40 + quad*8]);
            acc[nt] = __builtin_amdgcn_mfma_f32_16x16x32_bf16(af, bfr, acc[nt], 0, 0, 0);
        }
        __syncthreads();
    }

    const int rowb = m0 + wave*16 + quad*4;
    float aval = (epi == 2) ? alpha[0] : 0.f;
    #pragma unroll
    for (int nt = 0; nt < 4; nt++){
        int col = n0 + nt*16 + l16;
        if (col >= Nn) continue;
        float bvv = epi ? bias[col] : 0.f;
        #pragma unroll
        for (int r = 0; r < 4; r++){
            int row = rowb + r;
            if (row < M){
                float v = acc[nt][r] + bvv;
                if (epi == 2 && v < 0.f) v *= aval;
                if (obf) ((unsigned short*)Cv)[(long)row*Cstride + col] = f2b(v);
                else     ((float*)Cv)[(long)row*Cstride + col] = v;
            }
        }
    }
}

__global__ __launch_bounds__(256) void gemm_bt_ex(
    const unsigned short* __restrict__ A,
    const unsigned short* __restrict__ BT,
    void* __restrict__ Cv,
    int M, int Nn, int K, int Cstride,
    const float* __restrict__ bias,
    const float* __restrict__ alpha,
    int epi, const int* __restrict__ ridx, int obf)
{
    gemm_bt_body(A, BT, Cv, M, Nn, K, Cstride, bias, alpha, epi, ridx, obf);
}

// z-batched pair variant: blockIdx.z selects the (A,B,C,bias,alpha) set.
__global__ __launch_bounds__(256) void gemm_bt2(
    const unsigned short* __restrict__ A0, const unsigned short* __restrict__ A1,
    const unsigned short* __restrict__ B0, const unsigned short* __restrict__ B1,
    void* __restrict__ C0, void* __restrict__ C1,
    int M, int Nn, int K, int Cstride,
    const float* __restrict__ bias0, const float* __restrict__ bias1,
    const float* __restrict__ al0, const float* __restrict__ al1,
    int epi, const int* __restrict__ ridx, int obf)
{
    if (blockIdx.z == 0)
        gemm_bt_body(A0, B0, C0, M, Nn, K, Cstride, bias0, al0, epi, ridx, obf);
    else
        gemm_bt_body(A1, B1, C1, M, Nn, K, Cstride, bias1, al1, epi, ridx, obf);
}

// ---------------- fused GCN layer-1 aggregation (pos + neg), bf16 I/O ----------------

__global__ __launch_bounds__(256) void agg1_k(const unsigned short* __restrict__ XW,
    const float* __restrict__ ptW, const float* __restrict__ ntW,
    const int* __restrict__ flag, const int* __restrict__ negsrc,
    const float* __restrict__ dinv, const int* __restrict__ rowptr,
    const int* __restrict__ degi, const int* __restrict__ adj,
    const float* __restrict__ sb1, const float* __restrict__ sav,
    const float* __restrict__ tb1, const float* __restrict__ tav,
    unsigned short* __restrict__ H1p, unsigned short* __restrict__ H1n)
{
    int i = blockIdx.x; int t = threadIdx.x;
    int c = 2*t;                       // cols c, c+1 in [0,512)
    float di = dinv[i];
    int rs = rowptr[i], re = rs + degi[i];
    float p0 = ptW[c], p1 = ptW[c+1];
    float n0v = ntW[c], n1v = ntW[c+1];
    int fi = flag[i];
    int nsi = negsrc[i]; if (nsi < 0) nsi = 0;
    float ffi = fi ? 1.f : 0.f;
    float2 xp = bpair(*(const unsigned int*)(XW + (long)i*1024 + c));
    float2 xn = bpair(*(const unsigned int*)(XW + (long)nsi*1024 + 512 + c));
    float pa0 = (xp.x + ffi*p0) * di;
    float pa1 = (xp.y + ffi*p1) * di;
    float na0 = (fi ? n0v : xn.x) * di;
    float na1 = (fi ? n1v : xn.y) * di;
    for (int e = rs; e < re; ++e){
        int s = adj[e]; float ds = dinv[s];
        int fs = flag[s];
        int ns = negsrc[s]; if (ns < 0) ns = 0;
        float ffs = fs ? 1.f : 0.f;
        float2 sp = bpair(*(const unsigned int*)(XW + (long)s*1024 + c));
        float2 sn = bpair(*(const unsigned int*)(XW + (long)ns*1024 + 512 + c));
        pa0 += (sp.x + ffs*p0) * ds;
        pa1 += (sp.y + ffs*p1) * ds;
        na0 += (fs ? n0v : sn.x) * ds;
        na1 += (fs ? n1v : sn.y) * ds;
    }
    float sa_ = sav[0], ta_ = tav[0];
    float v0 = di*pa0 + sb1[c];   if (v0 < 0.f) v0 *= sa_;
    float v1 = di*pa1 + sb1[c+1]; if (v1 < 0.f) v1 *= sa_;
    float w0 = di*na0 + tb1[c];   if (w0 < 0.f) w0 *= ta_;
    float w1 = di*na1 + tb1[c+1]; if (w1 < 0.f) w1 *= ta_;
    *(unsigned int*)(H1p + (long)i*512 + c) = packb(v0, v1);
    *(unsigned int*)(H1n + (long)i*512 + c) = packb(w0, w1);
}

__global__ __launch_bounds__(128) void agg128_k(const unsigned short* __restrict__ In,
    const float* __restrict__ dinv, const int* __restrict__ rowptr,
    const int* __restrict__ degi, const int* __restrict__ adj,
    const float* __restrict__ b2, const float* __restrict__ a2,
    unsigned short* __restrict__ Out)
{
    int i = blockIdx.x, t = threadIdx.x;
    float di = dinv[i];
    int rs = rowptr[i], re = rs + degi[i];
    float acc = b2f(In[(long)i*128 + t]) * di;
    for (int e = rs; e < re; ++e){
        int s = adj[e];
        acc += b2f(In[(long)s*128 + t]) * dinv[s];
    }
    float v = di*acc + b2[t];
    float a = a2[0]; if (v < 0.f) v *= a;
    Out[(long)i*128 + t] = f2b(v);
}

__global__ __launch_bounds__(128) void aggrec_k(const unsigned short* __restrict__ recPre,
    const float* __restrict__ dinv, const int* __restrict__ rowptr,
    const int* __restrict__ degi, const int* __restrict__ adj,
    const int* __restrict__ flag, const int* __restrict__ perm,
    unsigned short* __restrict__ recAgg)
{
    int b = blockIdx.x, t = threadIdx.x;
    int i = perm[b];
    float di = dinv[i];
    int rs = rowptr[i], re = rs + degi[i];
    float acc = 0.f; // self loop: i is a mask node -> rec row zeroed
    for (int e = rs; e < re; ++e){
        int s = adj[e];
        if (!flag[s]) acc += b2f(recPre[(long)s*128 + t]) * dinv[s];
    }
    recAgg[(long)b*128 + t] = f2b(di * acc);
}

// ---------------- DGI head ----------------

__global__ __launch_bounds__(128) void meanp_k(const float* __restrict__ posZ,
                                               float* svecraw){
    int j = threadIdx.x;
    int r0 = blockIdx.x*64, r1 = r0 + 64; if (r1 > NM) r1 = NM;
    float s = 0.f;
    for (int r = r0; r < r1; ++r) s += posZ[(long)r*128 + j];
    atomicAdd(&svecraw[j], s);
}

__global__ void ws_k(const float* __restrict__ dgiW, const float* __restrict__ svecraw,
                     float* wsv){
    __shared__ float s[128];
    int i = threadIdx.x; // 128
    s[i] = 1.f/(1.f + expf(-svecraw[i]/(float)NM));
    __syncthreads();
    float a = 0.f;
    for (int j = 0; j < 128; ++j) a += dgiW[i*128 + j] * s[j];
    wsv[i] = a;
}

// grid-stride rows; per-wave accumulate; 2 atomics per block (was 6000 total ->
// 78 us of same-address L2 atomic serialization; now ~256 atomics).
__global__ __launch_bounds__(256) void dgi_k(const float* __restrict__ posZ,
    const float* __restrict__ negZ, const float* __restrict__ wsv, float* scal){
    __shared__ float sp[4], sn[4];
    int wid = threadIdx.x >> 6, lane = threadIdx.x & 63;
    float w0 = wsv[lane], w1 = wsv[64 + lane];
    float accp = 0.f, accn = 0.f;
    for (int row = blockIdx.x*4 + wid; row < 2*NM; row += gridDim.x*4){
        const float* Z = (row < NM) ? posZ : negZ;
        int r = (row < NM) ? row : row - NM;
        float v = Z[(long)r*128 + lane] * w0 + Z[(long)r*128 + 64 + lane] * w1;
        for (int off = 32; off; off >>= 1) v += __shfl_down(v, off, 64);
        if (lane == 0){
            float d = 1.f/(1.f + expf(-v));
            if (row < NM) accp += logf(d + 1e-15f);
            else          accn += logf(1.f - d + 1e-15f);
        }
    }
    if (lane == 0){ sp[wid] = accp; sn[wid] = accn; }
    __syncthreads();
    if (threadIdx.x == 0){
        atomicAdd(&scal[0], sp[0]+sp[1]+sp[2]+sp[3]);
        atomicAdd(&scal[1], sn[0]+sn[1]+sn[2]+sn[3]);
    }
}

// ---------------- cosine feature loss ----------------

__global__ __launch_bounds__(256) void cos_k(const float* __restrict__ x,
    const unsigned short* __restrict__ recMask, const int* __restrict__ perm,
    float* scal){
    int b = blockIdx.x, t = threadIdx.x;
    long xi = (long)perm[b]*DD;
    long ri = (long)b*DD;
    float dot = 0.f, nx = 0.f, nr = 0.f;
    for (int d = t; d < DD; d += 256){
        float xv = x[xi + d], rv = b2f(recMask[ri + d]);
        dot += xv*rv; nx += xv*xv; nr += rv*rv;
    }
    for (int off = 32; off; off >>= 1){
        dot += __shfl_down(dot, off, 64);
        nx  += __shfl_down(nx,  off, 64);
        nr  += __shfl_down(nr,  off, 64);
    }
    __shared__ float sd[4], sx[4], sr[4];
    int w = t >> 6, lane = t & 63;
    if (lane == 0){ sd[w] = dot; sx[w] = nx; sr[w] = nr; }
    __syncthreads();
    if (t == 0){
        float Dv = sd[0]+sd[1]+sd[2]+sd[3];
        float Xv = sx[0]+sx[1]+sx[2]+sx[3];
        float Rv = sr[0]+sr[1]+sr[2]+sr[3];
        float c = Dv/(fmaxf(sqrtf(Xv),1e-12f)*fmaxf(sqrtf(Rv),1e-12f));
        float e = 1.f - c;
        atomicAdd(&scal[16 + (b & 63)], e*e);   // 64-way spread -> ~47 per slot
    }
}

__global__ void fin_k(const float* __restrict__ scal, float* out){
    float fs = 0.f;
    for (int i = 0; i < 64; ++i) fs += scal[16 + i];
    float feat = fs/(float)NM;
    float dgi  = -(scal[0]/(float)NM) - (scal[1]/(float)NM);
    out[0] = feat;
    out[1] = dgi;
}

// ---------------- launch ----------------

extern "C" void kernel_launch(void* const* d_in, const int* in_sizes, int n_in,
                              void* d_out, int out_size, void* d_ws, size_t ws_size,
                              hipStream_t stream) {
    (void)in_sizes; (void)n_in; (void)out_size; (void)d_ws; (void)ws_size;
    const float* x  = (const float*)d_in[0];
    const int* ei   = (const int*)d_in[1];
    const int* perm = (const int*)d_in[2];
    const int* shuf = (const int*)d_in[3];
    const float* sW1 = (const float*)d_in[4];
    const float* sb1 = (const float*)d_in[5];
    const float* sa  = (const float*)d_in[6];
    const float* sW2 = (const float*)d_in[7];
    const float* sb2 = (const float*)d_in[8];
    const float* tW1 = (const float*)d_in[9];
    const float* tb1 = (const float*)d_in[10];
    const float* ta  = (const float*)d_in[11];
    const float* tW2 = (const float*)d_in[12];
    const float* tb2 = (const float*)d_in[13];
    const float* pW1 = (const float*)d_in[14];
    const float* pb1 = (const float*)d_in[15];
    const float* pa  = (const float*)d_in[16];
    const float* pW2 = (const float*)d_in[17];
    const float* pb2 = (const float*)d_in[18];
    const float* tpW1 = (const float*)d_in[19];
    const float* tpb1 = (const float*)d_in[20];
    const float* tpa  = (const float*)d_in[21];
    const float* tpW2 = (const float*)d_in[22];
    const float* tpb2 = (const float*)d_in[23];
    const float* dgiW = (const float*)d_in[24];
    const float* posT = (const float*)d_in[25];
    const float* negT = (const float*)d_in[26];
    const float* e2dW = (const float*)d_in[27];
    const float* dW   = (const float*)d_in[28];
    const float* db   = (const float*)d_in[29];
    float* out = (float*)d_out;

    void* wsp = nullptr;
    hipGetSymbolAddress(&wsp, HIP_SYMBOL(g_ws));
    char* base = (char*)wsp;
    size_t off = 0;
    auto alloc = [&](size_t b){ size_t o = off; off = (off + b + 255) & ~(size_t)255; return o; };

    float* dinv    = (float*)(base + alloc(NND*4));
    int* degi      = (int*)  (base + alloc(NND*4));
    int* rowptr    = (int*)  (base + alloc(NND*4));
    int* cursor    = (int*)  (base + alloc(NND*4));
    int* adj       = (int*)  (base + alloc(EE*4));
    int* flag      = (int*)  (base + alloc(NND*4));
    int* negsrc    = (int*)  (base + alloc(NND*4));
    int* ecnt      = (int*)  (base + alloc(16*4));
    float* ptW     = (float*)(base + alloc(HH*4));
    float* ntW     = (float*)(base + alloc(HH*4));
    float* svecraw = (float*)(base + alloc(128*4));
    float* wsv     = (float*)(base + alloc(128*4));
    float* scal    = (float*)(base + alloc(80*4));

    unsigned short* xb    = (unsigned short*)(base + alloc((size_t)MP*KP*2));
    unsigned short* W1T   = (unsigned short*)(base + alloc((size_t)NW*KP*2));
    unsigned short* sW2T  = (unsigned short*)(base + alloc((size_t)LL*HH*2));
    unsigned short* tW2T  = (unsigned short*)(base + alloc((size_t)LL*HH*2));
    unsigned short* pW1T  = (unsigned short*)(base + alloc((size_t)PP*LL*2));
    unsigned short* pW2T  = (unsigned short*)(base + alloc((size_t)LL*PP*2));
    unsigned short* tpW1T = (unsigned short*)(base + alloc((size_t)PP*LL*2));
    unsigned short* tpW2T = (unsigned short*)(base + alloc((size_t)LL*PP*2));
    unsigned short* e2dWT = (unsigned short*)(base + alloc((size_t)LL*LL*2));
    unsigned short* dWT   = (unsigned short*)(base + alloc((size_t)DD*LL*2));

    unsigned short* XW      = (unsigned short*)(base + alloc((size_t)NND*1024*2));
    unsigned short* H1p     = (unsigned short*)(base + alloc((size_t)NND*512*2));
    unsigned short* H1n     = (unsigned short*)(base + alloc((size_t)NND*512*2));
    unsigned short* M2p     = (unsigned short*)(base + alloc((size_t)NND*128*2));
    unsigned short* M2n     = (unsigned short*)(base + alloc((size_t)NND*128*2));
    unsigned short* repP    = (unsigned short*)(base + alloc((size_t)NND*128*2));
    unsigned short* repN    = (unsigned short*)(base + alloc((size_t)NND*128*2));
    unsigned short* posH    = (unsigned short*)(base + alloc((size_t)NM*256*2));
    unsigned short* negH    = (unsigned short*)(base + alloc((size_t)NM*256*2));
    float* posZ             = (float*)(base + alloc((size_t)NM*128*4));
    float* negZ             = (float*)(base + alloc((size_t)NM*128*4));
    unsigned short* recPre  = (unsigned short*)(base + alloc((size_t)NND*128*2));
    unsigned short* recAgg  = (unsigned short*)(base + alloc((size_t)NM*128*2));
    unsigned short* recMask = (unsigned short*)(base + alloc((size_t)NM*DD*2));

    // ---- graph build (scan-free) ----
    init_k<<<(NND+255)/256, 256, 0, stream>>>(degi, cursor, scal, ptW, ntW, svecraw, ecnt);
    flag_k<<<(NND+255)/256, 256, 0, stream>>>(perm, shuf, flag, negsrc);
    count_k<<<(EE+255)/256, 256, 0, stream>>>(ei, degi);
    alloc_k<<<(NND+255)/256, 256, 0, stream>>>(degi, dinv, rowptr, ecnt);
    fill_k<<<(EE+255)/256, 256, 0, stream>>>(ei, rowptr, cursor, adj);
    tok_k<<<dim3(2,8), 512, 0, stream>>>(posT, negT, sW1, tW1, ptW, ntW);

    // ---- bf16 staging ----
    cast_pad_x_k<<<(int)(((long)MP*(KP/8) + 255)/256), 256, 0, stream>>>(x, xb);
    {
        TBatch tb;
        const float* ins[10] = {sW1, tW1, sW2, tW2, pW1, pW2, tpW1, tpW2, e2dW, dW};
        unsigned short* outs[10] = {W1T, W1T + (size_t)HH*KP, sW2T, tW2T, pW1T, pW2T,
                                    tpW1T, tpW2T, e2dWT, dWT};
        int Rs[10]  = {DD, DD, HH, HH, LL, PP, LL, PP, LL, LL};
        int Cs[10]  = {HH, HH, LL, LL, PP, LL, PP, LL, LL, DD};
        int OSs[10] = {KP, KP, HH, HH, LL, PP, LL, PP, LL, LL};
        int cum = 0;
        for (int d = 0; d < 10; d++){
            tb.in[d] = ins[d]; tb.out[d] = outs[d];
            tb.R[d] = Rs[d]; tb.C[d] = Cs[d]; tb.OS[d] = OSs[d];
            tb.t0[d] = cum;
            cum += (OSs[d]/32) * ((Cs[d] + 31)/32);
        }
        tb.t0[10] = cum;
        transbatch_k<<<cum, dim3(32,8), 0, stream>>>(tb);
    }

    // ---- encoder layer 1 (MFMA 320x128, 256 blocks) + fused aggregation ----
    gemm320<<<256, 512, 0, stream>>>(xb, W1T, XW, NND, 1024);
    agg1_k<<<NND, 256, 0, stream>>>(XW, ptW, ntW, flag, negsrc, dinv, rowptr, degi, adj,
                                    sb1, sa, tb1, ta, H1p, H1n);

    // ---- encoder layer 2 (MFMA, z-batched pair) ----
    gemm_bt2<<<dim3(2,157,2), 256, 0, stream>>>(H1p, H1n, sW2T, tW2T, M2p, M2n,
                                                NND, LL, HH, LL,
                                                nullptr, nullptr, nullptr, nullptr,
                                                0, nullptr, 1);
    agg128_k<<<NND, 128, 0, stream>>>(M2p, dinv, rowptr, degi, adj, sb2, sa, repP);
    agg128_k<<<NND, 128, 0, stream>>>(M2n, dinv, rowptr, degi, adj, tb2, ta, repN);

    // ---- projections on mask rows (MFMA, gathered A via perm, z-batched) ----
    gemm_bt2<<<dim3(4,47,2), 256, 0, stream>>>(repP, repN, pW1T, tpW1T, posH, negH,
                                               NM, PP, LL, PP,
                                               pb1, tpb1, pa, tpa, 2, perm, 1);
    gemm_bt2<<<dim3(2,47,2), 256, 0, stream>>>(posH, negH, pW2T, tpW2T, posZ, negZ,
                                               NM, LL, PP, LL,
                                               pb2, tpb2, nullptr, nullptr, 1, nullptr, 0);

    // ---- DGI loss ----
    meanp_k<<<47, 128, 0, stream>>>(posZ, svecraw);
    ws_k<<<1, 128, 0, stream>>>(dgiW, svecraw, wsv);
    dgi_k<<<128, 256, 0, stream>>>(posZ, negZ, wsv, scal);

    // ---- decoder + feature loss (MFMA) ----
    gemm_bt_ex<<<dim3(2,157), 256, 0, stream>>>(repP, e2dWT, recPre, NND, LL, LL, LL,
                                                nullptr, nullptr, 0, nullptr, 1);
    aggrec_k<<<NM, 128, 0, stream>>>(recPre, dinv, rowptr, degi, adj, flag, perm, recAgg);
    gemm_bt_ex<<<dim3(47,47), 256, 0, stream>>>(recAgg, dWT, recMask, NM, DD, LL, DD,
                                                db, nullptr, 1, nullptr, 1);
    cos_k<<<NM, 256, 0, stream>>>(x, recMask, perm, scal);

    fin_k<<<1, 1, 0, stream>>>(scal, out);
}

// Round 5
// 509.626 us; speedup vs baseline: 1.3433x; 1.0282x over previous
//
#include <hip/hip_runtime.h>

#define NND 10000
#define EE  60000
#define DD  3000
#define HH  512
#define LL  128
#define PP  256
#define NM  3000

// padded dims for the big MFMA GEMM (no tail guards in hot loop)
#define KP  3072            // 48 * 64
#define MP  10240           // 32 * 320
#define NW  1024            // [sW1|tW1] fused width, 8*128
#define KTILES (KP/64)      // 48

// gemm320 tile geometry
#define BMT 320
#define BNT 128
#define AH_STR 10240        // elems per A k-half (320 rows x 32)
#define AB_STR 20480        // elems per A buf (2 k-halves)
#define BH_STR 4096         // elems per B k-half (128 rows x 32)
#define BB_STR 8192         // elems per B buf

typedef short bf16x8 __attribute__((ext_vector_type(8)));
typedef float f32x4 __attribute__((ext_vector_type(4)));

// All scratch lives in module BSS -> no dependency on harness ws_size.
__device__ __align__(256) char g_ws[(size_t)176 << 20];

__device__ __forceinline__ unsigned short f2b(float f){
    unsigned int x = __float_as_uint(f);
    unsigned int r = x + 0x7FFFu + ((x >> 16) & 1u);
    return (unsigned short)(r >> 16);
}
__device__ __forceinline__ float b2f(unsigned short u){
    return __uint_as_float(((unsigned int)u) << 16);
}
// uint holding 2 bf16 (low = col c, high = col c+1)
__device__ __forceinline__ float2 bpair(unsigned int u){
    float2 r;
    r.x = __uint_as_float(u << 16);
    r.y = __uint_as_float(u & 0xffff0000u);
    return r;
}
__device__ __forceinline__ unsigned int packb(float a, float b){
    return (unsigned int)f2b(a) | ((unsigned int)f2b(b) << 16);
}

__device__ __forceinline__ void gl_lds16(const void* g, void* l){
    __builtin_amdgcn_global_load_lds(
        (const __attribute__((address_space(1))) unsigned int*)g,
        (__attribute__((address_space(3))) unsigned int*)l, 16, 0, 0);
}

// ---------------- init / graph build ----------------

__global__ void init_k(int* degi, int* cursor, float* scal,
                       float* ptW, float* ntW, float* svecraw, int* ecnt){
    int i = blockIdx.x*256 + threadIdx.x;
    if (i < NND){ degi[i]=0; cursor[i]=0; }
    if (i < 80) scal[i]=0.f;           // [0]=dgi-pos [1]=dgi-neg [16..79]=cos slots
    if (i == 0) ecnt[0]=0;
    if (i < 128) svecraw[i]=0.f;
    if (i < HH){ ptW[i]=0.f; ntW[i]=0.f; }
}

// merged: degree count (i < EE) + mask flags (i < NND)
__global__ void build_k(const int* __restrict__ ei,
                        const int* __restrict__ perm, const int* __restrict__ shuf,
                        int* degi, int* flag, int* negsrc){
    int i = blockIdx.x*256 + threadIdx.x;
    if (i < EE) atomicAdd(&degi[ei[EE + i]], 1);
    if (i < NND){
        int p = perm[i];
        if (i < NM){ flag[p] = 1; negsrc[p] = -1; }
        else       { flag[p] = 0; negsrc[p] = perm[NM + shuf[i - NM]]; }
    }
}

// dinv + CSR segment allocation (order-free; per-block scan, 1 atomic/block)
__global__ __launch_bounds__(256) void alloc_k(const int* __restrict__ degi,
                                               float* dinv, int* rowptr, int* ecnt){
    __shared__ int sb[256];
    __shared__ int bbase;
    int t = threadIdx.x;
    int i = blockIdx.x*256 + t;
    int v = (i < NND) ? degi[i] : 0;
    sb[t] = v;
    __syncthreads();
    for (int off = 1; off < 256; off <<= 1){
        int x = 0;
        if (t >= off) x = sb[t - off];
        __syncthreads();
        sb[t] += x;
        __syncthreads();
    }
    if (t == 255) bbase = atomicAdd(ecnt, sb[255]);
    __syncthreads();
    if (i < NND){
        rowptr[i] = bbase + sb[t] - v;
        dinv[i] = 1.f/sqrtf((float)(degi[i] + 1));
    }
}

__global__ void fill_k(const int* __restrict__ ei, const int* __restrict__ rowptr,
                       int* cursor, int* adj){
    int i = blockIdx.x*256 + threadIdx.x;
    if (i < EE){
        int d = ei[EE + i];
        int s = ei[i];
        int p = atomicAdd(&cursor[d], 1);
        adj[rowptr[d] + p] = s;
    }
}

// token @ W1 partial sums; grid (2, 64) -> 128 blocks (was 16: only 16 CUs busy)
__global__ __launch_bounds__(512) void tok_k(const float* __restrict__ posT,
        const float* __restrict__ negT,
        const float* __restrict__ sW1, const float* __restrict__ tW1,
        float* ptW, float* ntW){
    int b = blockIdx.x; int chunk = blockIdx.y; int j = threadIdx.x;
    const float* tok = b ? negT : posT;
    const float* Wm  = b ? tW1  : sW1;
    float acc = 0.f;
    int d0 = chunk * 47, d1 = d0 + 47; if (d1 > DD) d1 = DD;
    for (int d = d0; d < d1; ++d) acc += tok[d] * Wm[(long)d*HH + j];
    atomicAdd(&((b ? ntW : ptW)[j]), acc);
}

// ---------------- casts for MFMA path ----------------

__global__ __launch_bounds__(256) void cast_pad_x_k(const float* __restrict__ x,
                                                    unsigned short* __restrict__ xb){
    long idx = (long)blockIdx.x*256 + threadIdx.x;
    if (idx >= (long)MP*(KP/8)) return;
    int row = (int)(idx / (KP/8));
    int g   = (int)(idx % (KP/8));
    unsigned short o[8] = {0,0,0,0,0,0,0,0};
    if (row < NND && g < DD/8){
        const float* src = x + (long)row*DD + g*8;
        float4 a = *(const float4*)(src);
        float4 b = *(const float4*)(src + 4);
        o[0]=f2b(a.x); o[1]=f2b(a.y); o[2]=f2b(a.z); o[3]=f2b(a.w);
        o[4]=f2b(b.x); o[5]=f2b(b.y); o[6]=f2b(b.z); o[7]=f2b(b.w);
    }
    *(uint4*)(xb + (long)row*KP + g*8) = *(const uint4*)o;
}

// batched transpose-cast: out[c*OS + r] = bf16(in[r*C + c]), zero-fill r in [R,OS)
struct TBatch {
    const float* in[10];
    unsigned short* out[10];
    int R[10], C[10], OS[10];
    int t0[11];
};

__global__ void transbatch_k(TBatch tb){
    __shared__ unsigned short tile[32][33];
    int b = blockIdx.x;
    int d = 0;
    while (d < 9 && b >= tb.t0[d+1]) d++;
    const float* in = tb.in[d];
    unsigned short* out = tb.out[d];
    int R = tb.R[d], C = tb.C[d], OS = tb.OS[d];
    int lt = b - tb.t0[d];
    int Ctiles = (C + 31) >> 5;
    int rt = lt / Ctiles, ct = lt % Ctiles;
    int rb = rt*32, cb = ct*32;
    int tx = threadIdx.x, ty = threadIdx.y; // (32,8)
    for (int i = ty; i < 32; i += 8){
        int r = rb + i, c = cb + tx;
        tile[i][tx] = (r < R && c < C) ? f2b(in[(long)r*C + c]) : (unsigned short)0;
    }
    __syncthreads();
    for (int i = ty; i < 32; i += 8){
        int c = cb + i, r = rb + tx;
        if (c < C && r < OS) out[(long)c*OS + r] = (r < R) ? tile[tx][i] : (unsigned short)0;
    }
}

// ---------------- 320x128 MFMA GEMM, 256 blocks (1/CU), 2-barrier tiles --------
// A: MP x KP bf16, Bg: NW x KP bf16 (row = output col). C guarded to M rows.
// A triple-buffered (3 x 40 KiB), B double-buffered (2 x 16 KiB) = 152 KiB LDS.
// Per K-tile: [18 frag ds_reads + 4 A gl_lds][16 MFMA mt0-1] BAR_b
//             [1 A + 2 B gl_lds][24 MFMA mt2-4] vmcnt(7) BAR_c.
// Barrier audit (2 suffice): ds_read completion is IN-ORDER, so each wave's
// cluster-2 operand wait drains all 18 reads of the tile -> by BAR_c every
// wave's frag reads are complete. Hence staging A(t+2) into buf (t+2)%3 =
// A(t-1)'s buffer needs no extra barrier (t-1's reads drained before its
// BAR_c, which precedes tile t in program order). B(t+2) overwrites B(t)'s
// buffer -> after BAR_b (cluster-1's lgkm wait transitively drained all B
// reads, B issued first). GATE7+BAR_c: tile t+1's 7 staging loads drained
// (per-wave vmcnt + rendezvous = global visibility) before t+1 reads them.
// Swizzle (both-sides, rule 21): linear LDS dest; global source chunk pre-XOR'd
// with ((row>>3)&1)<<1; reads XOR the same involution. Zero bank conflicts (meas.).

#define LDA(PB, MT, KS) (*(const bf16x8*)&As[(PB) + (KS)*AH_STR + a_off + (MT)*512])
#define LDB(PB, NT, KS) (*(const bf16x8*)&Bs[(PB) + (KS)*BH_STR + b_off + (NT)*512])

#define STG_A(KT, PDST, P) gl_lds16(asrc[P] + ((KT)<<6), &As[(PDST) + adst[P]])
#define STG_B(KT, PDST, Q) gl_lds16(bsrc[Q] + ((KT)<<6), &Bs[(PDST) + bdst[Q]])

#define GATE7 asm volatile("s_waitcnt vmcnt(7)" ::: "memory")
#define GATE0 asm volatile("s_waitcnt vmcnt(0)" ::: "memory")
#define NOOPS ((void)0)
#define AFENCE asm volatile("" ::: "memory")
#define BARR  { AFENCE; __builtin_amdgcn_s_barrier(); AFENCE; }

#define TILE_BODY(S1_STMT, S2_STMT, GATE_STMT) {                                  \
    bf16x8 af_[5][2], bf_[4][2];                                                  \
    _Pragma("unroll") for (int nt = 0; nt < 4; ++nt){                             \
        bf_[nt][0] = LDB(pB, nt, 0); bf_[nt][1] = LDB(pB, nt, 1); }               \
    _Pragma("unroll") for (int mt = 0; mt < 5; ++mt){                             \
        af_[mt][0] = LDA(pA, mt, 0); af_[mt][1] = LDA(pA, mt, 1); }               \
    S1_STMT;                                                                      \
    __builtin_amdgcn_s_setprio(1);                                                \
    _Pragma("unroll") for (int ks = 0; ks < 2; ++ks)                              \
      _Pragma("unroll") for (int nt = 0; nt < 4; ++nt)                            \
        _Pragma("unroll") for (int mt = 0; mt < 2; ++mt)                          \
          acc[mt][nt] = __builtin_amdgcn_mfma_f32_16x16x32_bf16(af_[mt][ks], bf_[nt][ks], acc[mt][nt], 0,0,0); \
    __builtin_amdgcn_s_setprio(0);                                                \
    BARR;                                                                         \
    S2_STMT;                                                                      \
    __builtin_amdgcn_s_setprio(1);                                                \
    _Pragma("unroll") for (int ks = 0; ks < 2; ++ks)                              \
      _Pragma("unroll") for (int nt = 0; nt < 4; ++nt)                            \
        _Pragma("unroll") for (int mt = 2; mt < 5; ++mt)                          \
          acc[mt][nt] = __builtin_amdgcn_mfma_f32_16x16x32_bf16(af_[mt][ks], bf_[nt][ks], acc[mt][nt], 0,0,0); \
    __builtin_amdgcn_s_setprio(0);                                                \
    GATE_STMT;                                                                    \
    BARR;                                                                         \
}

__global__ __launch_bounds__(512, 2) void gemm320(
    const unsigned short* __restrict__ Ag,
    const unsigned short* __restrict__ Bg,
    unsigned short* __restrict__ C,
    int M, int Cstride)
{
    __shared__ __align__(1024) unsigned short As[3*AB_STR]; // 120 KiB
    __shared__ __align__(1024) unsigned short Bs[2*BB_STR]; //  32 KiB

    // bijective XCD-chunked swizzle (nwg = 256, 256 % 8 == 0)
    const int bid = blockIdx.x;
    const int swz = (bid & 7)*32 + (bid >> 3);
    const int m0 = (swz >> 3) * BMT;   // 32 m-tiles
    const int n0 = (swz & 7) * BNT;    // 8 n-tiles

    const int tid = threadIdx.x;
    const int w   = tid >> 6,  l = tid & 63;
    const int wm  = w >> 1,    wn = w & 1;      // 4(M) x 2(N) wave grid: 80x64/wave
    const int l16 = l & 15,    quad = l >> 4;

    // staging: lane l writes LDS row (g*16 + l>>2), physical chunk (l&3);
    // global source chunk pre-swizzled by row-bit3 = l bit5.
    const int schunk = (l & 3) ^ (((l >> 5) & 1) << 1);
    // reads: logical chunk 'quad' -> physical chunk quad ^ ((row>>3)&1)<<1
    const int rq8   = ((quad ^ (((l16 >> 3) & 1) << 1)) << 3);
    const int a_off = ((wm*80 + l16) << 5) + rq8;
    const int b_off = ((wn*64 + l16) << 5) + rq8;

    // per-wave staging source pointers / LDS dest offsets (static-indexed)
    const unsigned short* asrc[5]; int adst[5];
    #pragma unroll
    for (int p = 0; p < 5; ++p){
        int j = 5*w + p, kh = j/20, g = j - kh*20;
        asrc[p] = Ag + (long)(m0 + g*16 + (l >> 2))*KP + (kh << 5) + (schunk << 3);
        adst[p] = kh*AH_STR + g*512;
    }
    const unsigned short* bsrc[2]; int bdst[2];
    #pragma unroll
    for (int q = 0; q < 2; ++q){
        int j = 2*w + q, kh = j >> 3, g = j & 7;
        bsrc[q] = Bg + (long)(n0 + g*16 + (l >> 2))*KP + (kh << 5) + (schunk << 3);
        bdst[q] = kh*BH_STR + g*512;
    }

    f32x4 acc[5][4];
    #pragma unroll
    for (int i = 0; i < 5; ++i)
        #pragma unroll
        for (int j = 0; j < 4; ++j)
            #pragma unroll
            for (int r = 0; r < 4; ++r) acc[i][j][r] = 0.f;

    // prologue: A(0),B(0)->buf0 [7], A(1),B(1)->buf1 [7]; drain tile-0's 7 only.
    #pragma unroll
    for (int p = 0; p < 5; ++p) STG_A(0, 0, p);
    #pragma unroll
    for (int q = 0; q < 2; ++q) STG_B(0, 0, q);
    #pragma unroll
    for (int p = 0; p < 5; ++p) STG_A(1, AB_STR, p);
    #pragma unroll
    for (int q = 0; q < 2; ++q) STG_B(1, BB_STR, q);
    GATE7;
    BARR;

    int ab = 0, bb = 0;   // buf of tile t: ab = t%3, bb = t&1
    #pragma unroll 1
    for (int t = 0; t < KTILES-2; ++t){
        const int pA  = ab*AB_STR;
        const int pB  = bb*BB_STR;                   // B(t) buf == B(t+2) dest buf
        const int ab2 = (ab == 0) ? 2 : ab - 1;      // (t+2)%3
        const int pA2 = ab2*AB_STR;
        TILE_BODY({ STG_A(t+2,pA2,0); STG_A(t+2,pA2,1); STG_A(t+2,pA2,2); STG_A(t+2,pA2,3); },
                  { STG_A(t+2,pA2,4); STG_B(t+2,pB,0); STG_B(t+2,pB,1); },
                  GATE7)
        ab = (ab == 2) ? 0 : ab + 1;
        bb ^= 1;
    }
    // peeled tile KTILES-2: no staging; full drain (tile-45's loads -> tile-47 data)
    {
        const int pA = ab*AB_STR, pB = bb*BB_STR;
        TILE_BODY(NOOPS, NOOPS, GATE0)
        ab = (ab == 2) ? 0 : ab + 1;
        bb ^= 1;
    }
    // peeled tile KTILES-1: no staging, no gate
    {
        const int pA = ab*AB_STR, pB = bb*BB_STR;
        TILE_BODY(NOOPS, NOOPS, NOOPS)
    }

    // epilogue: C/D layout col=lane&15, row=quad*4+reg
    #pragma unroll
    for (int mt = 0; mt < 5; ++mt){
        const int rowb = m0 + wm*80 + mt*16 + quad*4;
        #pragma unroll
        for (int nt = 0; nt < 4; ++nt){
            const int col = n0 + wn*64 + nt*16 + l16;
            #pragma unroll
            for (int r = 0; r < 4; ++r){
                const int row = rowb + r;
                if (row < M) C[(long)row*Cstride + col] = f2b(acc[mt][nt][r]);
            }
        }
    }
}

// ---------------- 64x64 MFMA GEMM: C = A[ridx?] @ BT^T (+epi) ----------------
// A: MxK bf16, BT: NnxK bf16, K % 32 == 0. epi: 0 none, 1 +bias, 2 +bias+prelu.
// obf: output bf16 (else f32). ridx: optional A row gather.
__device__ __forceinline__ void gemm_bt_body(
    const unsigned short* __restrict__ A,
    const unsigned short* __restrict__ BT,
    void* __restrict__ Cv,
    int M, int Nn, int K, int Cstride,
    const float* __restrict__ bias,
    const float* __restrict__ alpha,
    int epi, const int* __restrict__ ridx, int obf)
{
    __shared__ __align__(16) unsigned short As[64*40];
    __shared__ __align__(16) unsigned short Bs[64*40];
    const int m0 = blockIdx.y*64, n0 = blockIdx.x*64;
    const int t = threadIdx.x;
    const int lrow = t >> 2, lk = (t & 3) * 8;
    const int wave = t >> 6, lane = t & 63;
    const int quad = lane >> 4, l16 = lane & 15;
    f32x4 acc[4];
    #pragma unroll
    for (int i = 0; i < 4; i++)
        for (int j = 0; j < 4; j++) acc[i][j] = 0.f;

    const bool arv = (m0 + lrow) < M;
    const bool brv = (n0 + lrow) < Nn;
    long arow = 0;
    if (arv) arow = ridx ? (long)ridx[m0 + lrow] : (long)(m0 + lrow);
    const long arowbase = arow * K;
    const long browbase = (long)(n0 + lrow) * K;

    for (int k0 = 0; k0 < K; k0 += 32){
        int gk = k0 + lk;
        uint4 av = {0u,0u,0u,0u};
        uint4 bv = {0u,0u,0u,0u};
        if (arv) av = *(const uint4*)(A + arowbase + gk);
        if (brv) bv = *(const uint4*)(BT + browbase + gk);
        *(uint4*)(&As[lrow*40 + lk]) = av;
        *(uint4*)(&Bs[lrow*40 + lk]) = bv;
        __syncthreads();
        bf16x8 af = *(const bf16x8*)(&As[(wave*16 + l16)*40 + quad*8]);
        #pragma unroll
        for (int nt = 0; nt < 4; nt++){
            bf16x8 bfr = *(const bf16x8*)(&Bs[(nt*16 + l16)*40 + quad*8]);
            acc[nt] = __builtin_amdgcn_mfma_f32_16x16x32_bf16(af, bfr, acc[nt], 0, 0, 0);
        }
        __syncthreads();
    }

    const int rowb = m0 + wave*16 + quad*4;
    float aval = (epi == 2) ? alpha[0] : 0.f;
    #pragma unroll
    for (int nt = 0; nt < 4; nt++){
        int col = n0 + nt*16 + l16;
        if (col >= Nn) continue;
        float bvv = epi ? bias[col] : 0.f;
        #pragma unroll
        for (int r = 0; r < 4; r++){
            int row = rowb + r;
            if (row < M){
                float v = acc[nt][r] + bvv;
                if (epi == 2 && v < 0.f) v *= aval;
                if (obf) ((unsigned short*)Cv)[(long)row*Cstride + col] = f2b(v);
                else     ((float*)Cv)[(long)row*Cstride + col] = v;
            }
        }
    }
}

__global__ __launch_bounds__(256) void gemm_bt_ex(
    const unsigned short* __restrict__ A,
    const unsigned short* __restrict__ BT,
    void* __restrict__ Cv,
    int M, int Nn, int K, int Cstride,
    const float* __restrict__ bias,
    const float* __restrict__ alpha,
    int epi, const int* __restrict__ ridx, int obf)
{
    gemm_bt_body(A, BT, Cv, M, Nn, K, Cstride, bias, alpha, epi, ridx, obf);
}

// z-batched pair variant: blockIdx.z selects the (A,B,C,bias,alpha) set.
__global__ __launch_bounds__(256) void gemm_bt2(
    const unsigned short* __restrict__ A0, const unsigned short* __restrict__ A1,
    const unsigned short* __restrict__ B0, const unsigned short* __restrict__ B1,
    void* __restrict__ C0, void* __restrict__ C1,
    int M, int Nn, int K, int Cstride,
    const float* __restrict__ bias0, const float* __restrict__ bias1,
    const float* __restrict__ al0, const float* __restrict__ al1,
    int epi, const int* __restrict__ ridx, int obf)
{
    if (blockIdx.z == 0)
        gemm_bt_body(A0, B0, C0, M, Nn, K, Cstride, bias0, al0, epi, ridx, obf);
    else
        gemm_bt_body(A1, B1, C1, M, Nn, K, Cstride, bias1, al1, epi, ridx, obf);
}

// 3-way fused launch: z=0/1 = projection-H (pos/neg, gathered rows, prelu),
// z=2 = decoder pre-matmul recPre (independent of both). Ragged grid with
// early-exit guards; launch (4, 157, 3).
__global__ __launch_bounds__(256) void gemm_bt3(
    const unsigned short* __restrict__ repP, const unsigned short* __restrict__ repN,
    const unsigned short* __restrict__ pW1T, const unsigned short* __restrict__ tpW1T,
    const unsigned short* __restrict__ e2dWT,
    unsigned short* __restrict__ posH, unsigned short* __restrict__ negH,
    unsigned short* __restrict__ recPre,
    const float* __restrict__ pb1, const float* __restrict__ tpb1,
    const float* __restrict__ pa, const float* __restrict__ tpa,
    const int* __restrict__ perm)
{
    int z = blockIdx.z;
    if (z == 0){
        if (blockIdx.y < 47)
            gemm_bt_body(repP, pW1T, posH, NM, PP, LL, PP, pb1, pa, 2, perm, 1);
    } else if (z == 1){
        if (blockIdx.y < 47)
            gemm_bt_body(repN, tpW1T, negH, NM, PP, LL, PP, tpb1, tpa, 2, perm, 1);
    } else {
        if (blockIdx.x < 2)
            gemm_bt_body(repP, e2dWT, recPre, NND, LL, LL, LL, nullptr, nullptr, 0, nullptr, 1);
    }
}

// ---------------- fused GCN layer-1 aggregation (pos + neg), bf16 I/O ----------------

__global__ __launch_bounds__(256) void agg1_k(const unsigned short* __restrict__ XW,
    const float* __restrict__ ptW, const float* __restrict__ ntW,
    const int* __restrict__ flag, const int* __restrict__ negsrc,
    const float* __restrict__ dinv, const int* __restrict__ rowptr,
    const int* __restrict__ degi, const int* __restrict__ adj,
    const float* __restrict__ sb1, const float* __restrict__ sav,
    const float* __restrict__ tb1, const float* __restrict__ tav,
    unsigned short* __restrict__ H1p, unsigned short* __restrict__ H1n)
{
    int i = blockIdx.x; int t = threadIdx.x;
    int c = 2*t;                       // cols c, c+1 in [0,512)
    float di = dinv[i];
    int rs = rowptr[i], re = rs + degi[i];
    float p0 = ptW[c], p1 = ptW[c+1];
    float n0v = ntW[c], n1v = ntW[c+1];
    int fi = flag[i];
    int nsi = negsrc[i]; if (nsi < 0) nsi = 0;
    float ffi = fi ? 1.f : 0.f;
    float2 xp = bpair(*(const unsigned int*)(XW + (long)i*1024 + c));
    float2 xn = bpair(*(const unsigned int*)(XW + (long)nsi*1024 + 512 + c));
    float pa0 = (xp.x + ffi*p0) * di;
    float pa1 = (xp.y + ffi*p1) * di;
    float na0 = (fi ? n0v : xn.x) * di;
    float na1 = (fi ? n1v : xn.y) * di;
    for (int e = rs; e < re; ++e){
        int s = adj[e]; float ds = dinv[s];
        int fs = flag[s];
        int ns = negsrc[s]; if (ns < 0) ns = 0;
        float ffs = fs ? 1.f : 0.f;
        float2 sp = bpair(*(const unsigned int*)(XW + (long)s*1024 + c));
        float2 sn = bpair(*(const unsigned int*)(XW + (long)ns*1024 + 512 + c));
        pa0 += (sp.x + ffs*p0) * ds;
        pa1 += (sp.y + ffs*p1) * ds;
        na0 += (fs ? n0v : sn.x) * ds;
        na1 += (fs ? n1v : sn.y) * ds;
    }
    float sa_ = sav[0], ta_ = tav[0];
    float v0 = di*pa0 + sb1[c];   if (v0 < 0.f) v0 *= sa_;
    float v1 = di*pa1 + sb1[c+1]; if (v1 < 0.f) v1 *= sa_;
    float w0 = di*na0 + tb1[c];   if (w0 < 0.f) w0 *= ta_;
    float w1 = di*na1 + tb1[c+1]; if (w1 < 0.f) w1 *= ta_;
    *(unsigned int*)(H1p + (long)i*512 + c) = packb(v0, v1);
    *(unsigned int*)(H1n + (long)i*512 + c) = packb(w0, w1);
}

// fused pos/neg second-layer aggregation: blockIdx.y selects the set.
__global__ __launch_bounds__(128) void agg128_k(
    const unsigned short* __restrict__ In0, const unsigned short* __restrict__ In1,
    const float* __restrict__ dinv, const int* __restrict__ rowptr,
    const int* __restrict__ degi, const int* __restrict__ adj,
    const float* __restrict__ b20, const float* __restrict__ b21,
    const float* __restrict__ a20, const float* __restrict__ a21,
    unsigned short* __restrict__ Out0, unsigned short* __restrict__ Out1)
{
    int i = blockIdx.x, t = threadIdx.x;
    int h = blockIdx.y;
    const unsigned short* In = h ? In1 : In0;
    const float* b2 = h ? b21 : b20;
    const float* a2 = h ? a21 : a20;
    unsigned short* Out = h ? Out1 : Out0;
    float di = dinv[i];
    int rs = rowptr[i], re = rs + degi[i];
    float acc = b2f(In[(long)i*128 + t]) * di;
    for (int e = rs; e < re; ++e){
        int s = adj[e];
        acc += b2f(In[(long)s*128 + t]) * dinv[s];
    }
    float v = di*acc + b2[t];
    float a = a2[0]; if (v < 0.f) v *= a;
    Out[(long)i*128 + t] = f2b(v);
}

__global__ __launch_bounds__(128) void aggrec_k(const unsigned short* __restrict__ recPre,
    const float* __restrict__ dinv, const int* __restrict__ rowptr,
    const int* __restrict__ degi, const int* __restrict__ adj,
    const int* __restrict__ flag, const int* __restrict__ perm,
    unsigned short* __restrict__ recAgg)
{
    int b = blockIdx.x, t = threadIdx.x;
    int i = perm[b];
    float di = dinv[i];
    int rs = rowptr[i], re = rs + degi[i];
    float acc = 0.f; // self loop: i is a mask node -> rec row zeroed
    for (int e = rs; e < re; ++e){
        int s = adj[e];
        if (!flag[s]) acc += b2f(recPre[(long)s*128 + t]) * dinv[s];
    }
    recAgg[(long)b*128 + t] = f2b(di * acc);
}

// ---------------- DGI head ----------------

__global__ __launch_bounds__(128) void meanp_k(const float* __restrict__ posZ,
                                               float* svecraw){
    int j = threadIdx.x;
    int r0 = blockIdx.x*64, r1 = r0 + 64; if (r1 > NM) r1 = NM;
    float s = 0.f;
    for (int r = r0; r < r1; ++r) s += posZ[(long)r*128 + j];
    atomicAdd(&svecraw[j], s);
}

__global__ void ws_k(const float* __restrict__ dgiW, const float* __restrict__ svecraw,
                     float* wsv){
    __shared__ float s[128];
    int i = threadIdx.x; // 128
    s[i] = 1.f/(1.f + expf(-svecraw[i]/(float)NM));
    __syncthreads();
    float a = 0.f;
    for (int j = 0; j < 128; ++j) a += dgiW[i*128 + j] * s[j];
    wsv[i] = a;
}

// grid-stride rows; per-wave accumulate; 2 atomics per block.
__global__ __launch_bounds__(256) void dgi_k(const float* __restrict__ posZ,
    const float* __restrict__ negZ, const float* __restrict__ wsv, float* scal){
    __shared__ float sp[4], sn[4];
    int wid = threadIdx.x >> 6, lane = threadIdx.x & 63;
    float w0 = wsv[lane], w1 = wsv[64 + lane];
    float accp = 0.f, accn = 0.f;
    for (int row = blockIdx.x*4 + wid; row < 2*NM; row += gridDim.x*4){
        const float* Z = (row < NM) ? posZ : negZ;
        int r = (row < NM) ? row : row - NM;
        float v = Z[(long)r*128 + lane] * w0 + Z[(long)r*128 + 64 + lane] * w1;
        for (int off = 32; off; off >>= 1) v += __shfl_down(v, off, 64);
        if (lane == 0){
            float d = 1.f/(1.f + expf(-v));
            if (row < NM) accp += logf(d + 1e-15f);
            else          accn += logf(1.f - d + 1e-15f);
        }
    }
    if (lane == 0){ sp[wid] = accp; sn[wid] = accn; }
    __syncthreads();
    if (threadIdx.x == 0){
        atomicAdd(&scal[0], sp[0]+sp[1]+sp[2]+sp[3]);
        atomicAdd(&scal[1], sn[0]+sn[1]+sn[2]+sn[3]);
    }
}

// ---------------- cosine feature loss ----------------

__global__ __launch_bounds__(256) void cos_k(const float* __restrict__ x,
    const unsigned short* __restrict__ recMask, const int* __restrict__ perm,
    float* scal){
    int b = blockIdx.x, t = threadIdx.x;
    long xi = (long)perm[b]*DD;
    long ri = (long)b*DD;
    float dot = 0.f, nx = 0.f, nr = 0.f;
    for (int d = t; d < DD; d += 256){
        float xv = x[xi + d], rv = b2f(recMask[ri + d]);
        dot += xv*rv; nx += xv*xv; nr += rv*rv;
    }
    for (int off = 32; off; off >>= 1){
        dot += __shfl_down(dot, off, 64);
        nx  += __shfl_down(nx,  off, 64);
        nr  += __shfl_down(nr,  off, 64);
    }
    __shared__ float sd[4], sx[4], sr[4];
    int w = t >> 6, lane = t & 63;
    if (lane == 0){ sd[w] = dot; sx[w] = nx; sr[w] = nr; }
    __syncthreads();
    if (t == 0){
        float Dv = sd[0]+sd[1]+sd[2]+sd[3];
        float Xv = sx[0]+sx[1]+sx[2]+sx[3];
        float Rv = sr[0]+sr[1]+sr[2]+sr[3];
        float c = Dv/(fmaxf(sqrtf(Xv),1e-12f)*fmaxf(sqrtf(Rv),1e-12f));
        float e = 1.f - c;
        atomicAdd(&scal[16 + (b & 63)], e*e);   // 64-way spread -> ~47 per slot
    }
}

__global__ void fin_k(const float* __restrict__ scal, float* out){
    float fs = 0.f;
    for (int i = 0; i < 64; ++i) fs += scal[16 + i];
    float feat = fs/(float)NM;
    float dgi  = -(scal[0]/(float)NM) - (scal[1]/(float)NM);
    out[0] = feat;
    out[1] = dgi;
}

// ---------------- launch ----------------

extern "C" void kernel_launch(void* const* d_in, const int* in_sizes, int n_in,
                              void* d_out, int out_size, void* d_ws, size_t ws_size,
                              hipStream_t stream) {
    (void)in_sizes; (void)n_in; (void)out_size; (void)d_ws; (void)ws_size;
    const float* x  = (const float*)d_in[0];
    const int* ei   = (const int*)d_in[1];
    const int* perm = (const int*)d_in[2];
    const int* shuf = (const int*)d_in[3];
    const float* sW1 = (const float*)d_in[4];
    const float* sb1 = (const float*)d_in[5];
    const float* sa  = (const float*)d_in[6];
    const float* sW2 = (const float*)d_in[7];
    const float* sb2 = (const float*)d_in[8];
    const float* tW1 = (const float*)d_in[9];
    const float* tb1 = (const float*)d_in[10];
    const float* ta  = (const float*)d_in[11];
    const float* tW2 = (const float*)d_in[12];
    const float* tb2 = (const float*)d_in[13];
    const float* pW1 = (const float*)d_in[14];
    const float* pb1 = (const float*)d_in[15];
    const float* pa  = (const float*)d_in[16];
    const float* pW2 = (const float*)d_in[17];
    const float* pb2 = (const float*)d_in[18];
    const float* tpW1 = (const float*)d_in[19];
    const float* tpb1 = (const float*)d_in[20];
    const float* tpa  = (const float*)d_in[21];
    const float* tpW2 = (const float*)d_in[22];
    const float* tpb2 = (const float*)d_in[23];
    const float* dgiW = (const float*)d_in[24];
    const float* posT = (const float*)d_in[25];
    const float* negT = (const float*)d_in[26];
    const float* e2dW = (const float*)d_in[27];
    const float* dW   = (const float*)d_in[28];
    const float* db   = (const float*)d_in[29];
    float* out = (float*)d_out;

    void* wsp = nullptr;
    hipGetSymbolAddress(&wsp, HIP_SYMBOL(g_ws));
    char* base = (char*)wsp;
    size_t off = 0;
    auto alloc = [&](size_t b){ size_t o = off; off = (off + b + 255) & ~(size_t)255; return o; };

    float* dinv    = (float*)(base + alloc(NND*4));
    int* degi      = (int*)  (base + alloc(NND*4));
    int* rowptr    = (int*)  (base + alloc(NND*4));
    int* cursor    = (int*)  (base + alloc(NND*4));
    int* adj       = (int*)  (base + alloc(EE*4));
    int* flag      = (int*)  (base + alloc(NND*4));
    int* negsrc    = (int*)  (base + alloc(NND*4));
    int* ecnt      = (int*)  (base + alloc(16*4));
    float* ptW     = (float*)(base + alloc(HH*4));
    float* ntW     = (float*)(base + alloc(HH*4));
    float* svecraw = (float*)(base + alloc(128*4));
    float* wsv     = (float*)(base + alloc(128*4));
    float* scal    = (float*)(base + alloc(80*4));

    unsigned short* xb    = (unsigned short*)(base + alloc((size_t)MP*KP*2));
    unsigned short* W1T   = (unsigned short*)(base + alloc((size_t)NW*KP*2));
    unsigned short* sW2T  = (unsigned short*)(base + alloc((size_t)LL*HH*2));
    unsigned short* tW2T  = (unsigned short*)(base + alloc((size_t)LL*HH*2));
    unsigned short* pW1T  = (unsigned short*)(base + alloc((size_t)PP*LL*2));
    unsigned short* pW2T  = (unsigned short*)(base + alloc((size_t)LL*PP*2));
    unsigned short* tpW1T = (unsigned short*)(base + alloc((size_t)PP*LL*2));
    unsigned short* tpW2T = (unsigned short*)(base + alloc((size_t)LL*PP*2));
    unsigned short* e2dWT = (unsigned short*)(base + alloc((size_t)LL*LL*2));
    unsigned short* dWT   = (unsigned short*)(base + alloc((size_t)DD*LL*2));

    unsigned short* XW      = (unsigned short*)(base + alloc((size_t)NND*1024*2));
    unsigned short* H1p     = (unsigned short*)(base + alloc((size_t)NND*512*2));
    unsigned short* H1n     = (unsigned short*)(base + alloc((size_t)NND*512*2));
    unsigned short* M2p     = (unsigned short*)(base + alloc((size_t)NND*128*2));
    unsigned short* M2n     = (unsigned short*)(base + alloc((size_t)NND*128*2));
    unsigned short* repP    = (unsigned short*)(base + alloc((size_t)NND*128*2));
    unsigned short* repN    = (unsigned short*)(base + alloc((size_t)NND*128*2));
    unsigned short* posH    = (unsigned short*)(base + alloc((size_t)NM*256*2));
    unsigned short* negH    = (unsigned short*)(base + alloc((size_t)NM*256*2));
    float* posZ             = (float*)(base + alloc((size_t)NM*128*4));
    float* negZ             = (float*)(base + alloc((size_t)NM*128*4));
    unsigned short* recPre  = (unsigned short*)(base + alloc((size_t)NND*128*2));
    unsigned short* recAgg  = (unsigned short*)(base + alloc((size_t)NM*128*2));
    unsigned short* recMask = (unsigned short*)(base + alloc((size_t)NM*DD*2));

    // ---- graph build (scan-free) ----
    init_k<<<(NND+255)/256, 256, 0, stream>>>(degi, cursor, scal, ptW, ntW, svecraw, ecnt);
    build_k<<<(EE+255)/256, 256, 0, stream>>>(ei, perm, shuf, degi, flag, negsrc);
    alloc_k<<<(NND+255)/256, 256, 0, stream>>>(degi, dinv, rowptr, ecnt);
    fill_k<<<(EE+255)/256, 256, 0, stream>>>(ei, rowptr, cursor, adj);
    tok_k<<<dim3(2,64), 512, 0, stream>>>(posT, negT, sW1, tW1, ptW, ntW);

    // ---- bf16 staging ----
    cast_pad_x_k<<<(int)(((long)MP*(KP/8) + 255)/256), 256, 0, stream>>>(x, xb);
    {
        TBatch tb;
        const float* ins[10] = {sW1, tW1, sW2, tW2, pW1, pW2, tpW1, tpW2, e2dW, dW};
        unsigned short* outs[10] = {W1T, W1T + (size_t)HH*KP, sW2T, tW2T, pW1T, pW2T,
                                    tpW1T, tpW2T, e2dWT, dWT};
        int Rs[10]  = {DD, DD, HH, HH, LL, PP, LL, PP, LL, LL};
        int Cs[10]  = {HH, HH, LL, LL, PP, LL, PP, LL, LL, DD};
        int OSs[10] = {KP, KP, HH, HH, LL, PP, LL, PP, LL, LL};
        int cum = 0;
        for (int d = 0; d < 10; d++){
            tb.in[d] = ins[d]; tb.out[d] = outs[d];
            tb.R[d] = Rs[d]; tb.C[d] = Cs[d]; tb.OS[d] = OSs[d];
            tb.t0[d] = cum;
            cum += (OSs[d]/32) * ((Cs[d] + 31)/32);
        }
        tb.t0[10] = cum;
        transbatch_k<<<cum, dim3(32,8), 0, stream>>>(tb);
    }

    // ---- encoder layer 1 (MFMA 320x128, 256 blocks) + fused aggregation ----
    gemm320<<<256, 512, 0, stream>>>(xb, W1T, XW, NND, 1024);
    agg1_k<<<NND, 256, 0, stream>>>(XW, ptW, ntW, flag, negsrc, dinv, rowptr, degi, adj,
                                    sb1, sa, tb1, ta, H1p, H1n);

    // ---- encoder layer 2 (MFMA, z-batched pair) + fused aggregation ----
    gemm_bt2<<<dim3(2,157,2), 256, 0, stream>>>(H1p, H1n, sW2T, tW2T, M2p, M2n,
                                                NND, LL, HH, LL,
                                                nullptr, nullptr, nullptr, nullptr,
                                                0, nullptr, 1);
    agg128_k<<<dim3(NND,2), 128, 0, stream>>>(M2p, M2n, dinv, rowptr, degi, adj,
                                              sb2, tb2, sa, ta, repP, repN);

    // ---- projections-H (pos+neg) + decoder recPre, one ragged z=3 launch ----
    gemm_bt3<<<dim3(4,157,3), 256, 0, stream>>>(repP, repN, pW1T, tpW1T, e2dWT,
                                                posH, negH, recPre,
                                                pb1, tpb1, pa, tpa, perm);
    gemm_bt2<<<dim3(2,47,2), 256, 0, stream>>>(posH, negH, pW2T, tpW2T, posZ, negZ,
                                               NM, LL, PP, LL,
                                               pb2, tpb2, nullptr, nullptr, 1, nullptr, 0);

    // ---- decoder aggregation + reconstruction ----
    aggrec_k<<<NM, 128, 0, stream>>>(recPre, dinv, rowptr, degi, adj, flag, perm, recAgg);
    gemm_bt_ex<<<dim3(47,47), 256, 0, stream>>>(recAgg, dWT, recMask, NM, DD, LL, DD,
                                                db, nullptr, 1, nullptr, 1);

    // ---- DGI loss ----
    meanp_k<<<47, 128, 0, stream>>>(posZ, svecraw);
    ws_k<<<1, 128, 0, stream>>>(dgiW, svecraw, wsv);
    dgi_k<<<128, 256, 0, stream>>>(posZ, negZ, wsv, scal);

    // ---- feature loss ----
    cos_k<<<NM, 256, 0, stream>>>(x, recMask, perm, scal);

    fin_k<<<1, 1, 0, stream>>>(scal, out);
}